// Round 1
// baseline (436.203 us; speedup 1.0000x reference)
//
#include <hip/hip_runtime.h>
#include <stdint.h>

// Channel attention (Restormer MDTA style). FP32 in/out, bf16 MFMA internals.
// R5: GEMM restructured for the K=192 geometry:
//   - A (weights wqkv / Mm) pre-arranged into MFMA fragment layout and preloaded
//     into registers ONCE per block (24 coalesced 16B loads/lane) — no A staging.
//   - B panel (128 n x 192 k) fully LDS-resident as six [128][32] chunks staged
//     via global_load_lds at block start -> ONE barrier per block (was 12).
//   - Slot-XOR swizzle (linear LDS dest + inverse-swizzled global source +
//     swizzled ds_read) kills the 4-way b128 read conflict (3.9M conflict cy).
//   - __launch_bounds__(256,2): 2 blocks/CU so staging overlaps compute.
// Pipeline per chunk of G batches:
//   transpose_f2b : x[b][c][p] f32 -> XT[b][p][c] bf16   (region1)
//   gemm_af<bf16> : qkv_pre = Wqkv . XT                  (M=576,N=16384,K=192)
//   dwconv2 qk    : qkv_pre ch[0,384) -> qk_post bf16    (region1, XT dead)
//   dwconv2 v     : qkv_pre ch[384,576) -> v_post        (class-0 slots of qkv_pre)
//   attn_scores   : S[bh] += q.k^T, norms += diag MFMA   (fp32 in ws)
//   softmax       : attn = softmax(temp * S / (|q||k|))
//   mproj         : MmF[b] = W_proj . blockdiag(attn)    (bf16, frag layout)
//   transpose_b   : v_post -> vT                         (class-1 slots)
//   gemm_af<f32>  : out = MmF . vT -> d_out fp32         (M=192,N=16384,K=192)

typedef __attribute__((ext_vector_type(8))) short bf16x8;
typedef __attribute__((ext_vector_type(4))) float f32x4;
typedef unsigned short u16;

#define HW 16384
#define CD 192
#define O3 576
#define KD 192

__device__ __forceinline__ float b2f(u16 u) {
    union { unsigned int i; float f; } v; v.i = ((unsigned int)u) << 16; return v.f;
}
__device__ __forceinline__ u16 f2b(float f) {
    union { float f; unsigned int i; } v; v.f = f;
    return (u16)((v.i + 0x7fffu + ((v.i >> 16) & 1u)) >> 16);  // RNE
}

__global__ __launch_bounds__(256) void fill_f32(float* p, long long n, float val) {
    long long stride = (long long)gridDim.x * 256;
    for (long long i = blockIdx.x * 256LL + threadIdx.x; i < n; i += stride) p[i] = val;
}

__global__ __launch_bounds__(256) void zerof(float* p, int n) {
    int i = blockIdx.x * 256 + threadIdx.x;
    if (i < n) p[i] = 0.f;
}

// W fp32 [M][192] -> fragment-layout bf16, rows padded to NF/48*128 with zeros.
// Frag F = rwmb*24 + mt*6 + ks  (rwmb = row>>6), holds rows rwmb*64+mt*16+[0,16)
// x k ks*32+[0,32). Within frag: lane = q*16+lr (q = (k%32)/8, lr = row%16),
// lane's 8 contiguous k at Af[F*512 + lane*8].
__global__ __launch_bounds__(256) void afrag_prep(
    const float* __restrict__ W, u16* __restrict__ Af, int M, int NF)
{
    int t = blockIdx.x * 256 + threadIdx.x;
    if (t >= NF * 64) return;
    int F = t >> 6, lane = t & 63;
    int ks = F % 6, mt = (F / 6) & 3, rwmb = F / 24;
    int row = rwmb * 64 + mt * 16 + (lane & 15);
    int k0 = ks * 32 + (lane >> 4) * 8;
    u16 v[8] __attribute__((aligned(16)));
    if (row < M) {
        const float* src = W + (long long)row * KD + k0;
#pragma unroll
        for (int j = 0; j < 8; j++) v[j] = f2b(src[j]);
    } else {
#pragma unroll
        for (int j = 0; j < 8; j++) v[j] = 0;
    }
    *(bf16x8*)&Af[(long long)F * 512 + lane * 8] = *(const bf16x8*)v;
}

// x[b][c][p] fp32 (ch stride HW) -> XT[b][p][c] bf16 (row stride CD). 64x64 tiles.
__global__ __launch_bounds__(256) void transpose_f2b(
    const float* __restrict__ in, u16* __restrict__ out,
    long long in_bs, long long out_bs)
{
    __shared__ u16 t[64 * 72];
    const int tid = threadIdx.x;
    const int p0 = blockIdx.x * 64, c0 = blockIdx.y * 64;
    const long long bz = blockIdx.z;
    const float* ib = in + bz * in_bs;
    u16* ob = out + bz * out_bs;
    {
        int cl = tid >> 2, pc = (tid & 3) * 16;
        const float* src = &ib[(long long)(c0 + cl) * HW + p0 + pc];
#pragma unroll
        for (int j4 = 0; j4 < 4; j4++) {
            f32x4 v = *(const f32x4*)(src + j4 * 4);
            u16* d = &t[cl * 72 + pc + j4 * 4];
            d[0] = f2b(v[0]); d[1] = f2b(v[1]); d[2] = f2b(v[2]); d[3] = f2b(v[3]);
        }
    }
    __syncthreads();
    {
        int pl = tid >> 2, cc = (tid & 3) * 16;
        u16 tmp[16] __attribute__((aligned(16)));
#pragma unroll
        for (int j = 0; j < 16; j++) tmp[j] = t[(cc + j) * 72 + pl];
        u16* dst = &ob[(long long)(p0 + pl) * CD + c0 + cc];
        *(bf16x8*)dst       = *(const bf16x8*)&tmp[0];
        *(bf16x8*)(dst + 8) = *(const bf16x8*)&tmp[8];
    }
}

// bf16 -> bf16 transpose (for v)
__global__ __launch_bounds__(256) void transpose_b(
    const u16* __restrict__ in, u16* __restrict__ out,
    long long in_bs, long long out_bs)
{
    __shared__ u16 t[64 * 72];
    const int tid = threadIdx.x;
    const int p0 = blockIdx.x * 64, c0 = blockIdx.y * 64;
    const long long bz = blockIdx.z;
    const u16* ib = in + bz * in_bs;
    u16* ob = out + bz * out_bs;
    {
        int cl = tid >> 2, pc = (tid & 3) * 16;
        const u16* src = &ib[(long long)(c0 + cl) * HW + p0 + pc];
        *(bf16x8*)&t[cl * 72 + pc]     = *(const bf16x8*)src;
        *(bf16x8*)&t[cl * 72 + pc + 8] = *(const bf16x8*)(src + 8);
    }
    __syncthreads();
    {
        int pl = tid >> 2, cc = (tid & 3) * 16;
        u16 tmp[16] __attribute__((aligned(16)));
#pragma unroll
        for (int j = 0; j < 16; j++) tmp[j] = t[(cc + j) * 72 + pl];
        u16* dst = &ob[(long long)(p0 + pl) * CD + c0 + cc];
        *(bf16x8*)dst       = *(const bf16x8*)&tmp[0];
        *(bf16x8*)(dst + 8) = *(const bf16x8*)&tmp[8];
    }
}

// Async global->LDS staging, 16B/lane at wave-uniform base + lane*16 (m97).
__device__ __forceinline__ void stage16(const u16* g, u16* l) {
    __builtin_amdgcn_global_load_lds((const __attribute__((address_space(1))) unsigned int*)g,
                                     (__attribute__((address_space(3))) unsigned int*)l, 16, 0, 0);
}

// C[b][m][n] = sum_k A[m][k]*Bt[b][n][k]; A pre-fragged bf16 (registers),
// B panel fully LDS-resident (6 x [128][32] chunks, slot-XOR swizzled),
// ONE barrier per block. 128x128 tile, 4 waves of 64x64.
template <bool OUT_F32>
__global__ __launch_bounds__(256, 2) void gemm_af(
    const u16* __restrict__ Afrag, const u16* __restrict__ Bt, void* __restrict__ Cv,
    int M, long long af_bs, long long b_bs, long long c_bs)
{
    __shared__ u16 lsB[6][128 * 32];  // 48 KiB
    const int tid = threadIdx.x;
    const int lane = tid & 63, wid = tid >> 6;
    const int n0 = blockIdx.x * 128, mb = blockIdx.y;
    const long long bz = blockIdx.z;
    const u16* Bb = Bt + bz * b_bs;
    const int wm = (wid & 1) * 64, wn = (wid >> 1) * 64;
    const int lr = lane & 15, quad = lane >> 4;

    // ---- stage ALL B chunks: linear LDS dest, slot-swizzled global source ----
    // LDS[row][slot s] holds G[row][k = ks*32 + (s ^ (row&3))*8 ..+7]
    {
        const int srow = lane >> 2;                       // row within 16-row group
        const int gslot = (lane & 3) ^ (srow & 3);        // row&3 == srow&3 (bases %4==0)
        const u16* gp = Bb + (long long)(n0 + wid * 32 + srow) * KD + gslot * 8;
#pragma unroll
        for (int ks = 0; ks < 6; ks++) {
            stage16(gp + ks * 32,               &lsB[ks][(wid * 32) * 32]);
            stage16(gp + 16 * KD + ks * 32,     &lsB[ks][(wid * 32 + 16) * 32]);
        }
    }
    // ---- preload A fragments from frag layout (coalesced, L2-hot) ----
    bf16x8 af[4][6];
    {
        const u16* Ap = Afrag + bz * af_bs
                      + ((long long)((mb * 2 + (wid & 1)) * 24)) * 512 + lane * 8;
#pragma unroll
        for (int mt = 0; mt < 4; mt++)
#pragma unroll
            for (int ks = 0; ks < 6; ks++)
                af[mt][ks] = *(const bf16x8*)(Ap + (mt * 6 + ks) * 512);
    }
    f32x4 acc[4][4];
#pragma unroll
    for (int i = 0; i < 4; i++)
#pragma unroll
        for (int j = 0; j < 4; j++) acc[i][j] = (f32x4){0.f, 0.f, 0.f, 0.f};

    __syncthreads();  // drains vmcnt: B in LDS, A in regs

    const int rslot = (quad ^ (lr & 3)) * 8;  // swizzled read slot
#pragma unroll
    for (int ks = 0; ks < 6; ks++) {
        bf16x8 bfv[4];
#pragma unroll
        for (int nt = 0; nt < 4; nt++)
            bfv[nt] = *(const bf16x8*)&lsB[ks][(wn + nt * 16 + lr) * 32 + rslot];
#pragma unroll
        for (int mt = 0; mt < 4; mt++)
#pragma unroll
            for (int nt = 0; nt < 4; nt++)
                acc[mt][nt] = __builtin_amdgcn_mfma_f32_16x16x32_bf16(af[mt][ks], bfv[nt], acc[mt][nt], 0, 0, 0);
    }
    // C/D layout: col = lane&15, row = quad*4 + reg
    const int m0 = mb * 128;
#pragma unroll
    for (int mt = 0; mt < 4; mt++)
#pragma unroll
        for (int r = 0; r < 4; r++) {
            int row = m0 + wm + mt * 16 + quad * 4 + r;
            if (row < M) {
#pragma unroll
                for (int nt = 0; nt < 4; nt++) {
                    int col = n0 + wn + nt * 16 + lr;
                    if (OUT_F32)
                        ((float*)Cv)[bz * c_bs + (long long)row * HW + col] = acc[mt][nt][r];
                    else
                        ((u16*)Cv)[bz * c_bs + (long long)row * HW + col] = f2b(acc[mt][nt][r]);
                }
            }
        }
}

// depthwise 3x3 SAME; in/out bf16, weights fp32 (weight row = wch0 + ch).
__global__ __launch_bounds__(256) void dwconv2(
    const u16* __restrict__ in, const float* __restrict__ wdw, u16* __restrict__ outp,
    long long in_bs, long long out_bs, int wch0)
{
    const int rt = blockIdx.x, ch = blockIdx.y, tid = threadIdx.x;
    const long long bz = blockIdx.z;
    const u16* ip = in + bz * in_bs + (long long)ch * HW;
    u16* op = outp + bz * out_bs + (long long)ch * HW;
    __shared__ float t[18 * 132];
    const int r0 = rt * 16;
    if (tid < 18) {
        t[tid * 132 + 0] = 0.f;   t[tid * 132 + 129] = 0.f;
        t[tid * 132 + 130] = 0.f; t[tid * 132 + 131] = 0.f;
    }
    for (int i = tid; i < 288; i += 256) {
        int rr = i >> 4, cc = (i & 15) * 8;
        int gr = r0 + rr - 1;
        float f[8];
        if (gr >= 0 && gr < 128) {
            bf16x8 v = *(const bf16x8*)(ip + gr * 128 + cc);
#pragma unroll
            for (int j = 0; j < 8; j++) f[j] = b2f((u16)v[j]);
        } else {
#pragma unroll
            for (int j = 0; j < 8; j++) f[j] = 0.f;
        }
#pragma unroll
        for (int j = 0; j < 8; j++) t[rr * 132 + 1 + cc + j] = f[j];
    }
    float w[9];
#pragma unroll
    for (int j = 0; j < 9; j++) w[j] = wdw[(wch0 + ch) * 9 + j];
    __syncthreads();
    const int rr = tid >> 4, c8 = (tid & 15) * 8;
    float o[8] = {0.f, 0.f, 0.f, 0.f, 0.f, 0.f, 0.f, 0.f};
#pragma unroll
    for (int dy = 0; dy < 3; dy++) {
        const float* row = &t[(rr + dy) * 132 + c8];  // LDS idx c8 == image col c8-1
        float r[12] __attribute__((aligned(16)));
        *(f32x4*)&r[0] = *(const f32x4*)row;
        *(f32x4*)&r[4] = *(const f32x4*)(row + 4);
        *(f32x4*)&r[8] = *(const f32x4*)(row + 8);
        const float w0 = w[dy * 3], w1 = w[dy * 3 + 1], w2 = w[dy * 3 + 2];
#pragma unroll
        for (int j = 0; j < 8; j++) o[j] += w0 * r[j] + w1 * r[j + 1] + w2 * r[j + 2];
    }
    u16 ob[8] __attribute__((aligned(16)));
#pragma unroll
    for (int j = 0; j < 8; j++) ob[j] = f2b(o[j]);
    *(bf16x8*)&op[(long long)(r0 + rr) * 128 + c8] = *(const bf16x8*)ob;
}

// S[bh][48][48] += q.k^T ; norms[bh][96] += diag(q.q^T), diag(k.k^T)
__global__ __launch_bounds__(256) void attn_scores(
    const u16* __restrict__ qk, float* __restrict__ S, float* __restrict__ norms,
    int bh0)
{
    const int tid = threadIdx.x, lane = tid & 63, wid = tid >> 6;
    const int kc = blockIdx.x, head = blockIdx.y;
    const long long bz = blockIdx.z;
    const u16* q = qk + bz * (2LL * CD * HW) + (long long)head * 48 * HW;
    const u16* k = q + (long long)CD * HW;
    const int lr = lane & 15, quad = lane >> 4;

    f32x4 sc[3][3], sq[3], sk[3];
#pragma unroll
    for (int i = 0; i < 3; i++) {
#pragma unroll
        for (int j = 0; j < 3; j++) sc[i][j] = (f32x4){0.f, 0.f, 0.f, 0.f};
        sq[i] = (f32x4){0.f, 0.f, 0.f, 0.f};
        sk[i] = (f32x4){0.f, 0.f, 0.f, 0.f};
    }
    const int n0 = kc * 1024 + wid * 256;
#pragma unroll 2
    for (int s = 0; s < 8; s++) {
        const int n = n0 + s * 32 + quad * 8;
        bf16x8 aq[3], ak[3];
#pragma unroll
        for (int t3 = 0; t3 < 3; t3++) {
            aq[t3] = *(const bf16x8*)(q + (long long)(t3 * 16 + lr) * HW + n);
            ak[t3] = *(const bf16x8*)(k + (long long)(t3 * 16 + lr) * HW + n);
        }
#pragma unroll
        for (int mt = 0; mt < 3; mt++)
#pragma unroll
            for (int nt = 0; nt < 3; nt++)
                sc[mt][nt] = __builtin_amdgcn_mfma_f32_16x16x32_bf16(aq[mt], ak[nt], sc[mt][nt], 0, 0, 0);
#pragma unroll
        for (int t3 = 0; t3 < 3; t3++) {
            sq[t3] = __builtin_amdgcn_mfma_f32_16x16x32_bf16(aq[t3], aq[t3], sq[t3], 0, 0, 0);
            sk[t3] = __builtin_amdgcn_mfma_f32_16x16x32_bf16(ak[t3], ak[t3], sk[t3], 0, 0, 0);
        }
    }
    __shared__ float sS[2304];
    __shared__ float snq[48], snk[48];
    for (int i = tid; i < 2304; i += 256) sS[i] = 0.f;
    if (tid < 48) { snq[tid] = 0.f; snk[tid] = 0.f; }
    __syncthreads();
#pragma unroll
    for (int mt = 0; mt < 3; mt++)
#pragma unroll
        for (int nt = 0; nt < 3; nt++)
#pragma unroll
            for (int r = 0; r < 4; r++)
                atomicAdd(&sS[(mt * 16 + quad * 4 + r) * 48 + nt * 16 + lr], sc[mt][nt][r]);
#pragma unroll
    for (int t3 = 0; t3 < 3; t3++)
#pragma unroll
        for (int r = 0; r < 4; r++) {
            int rw = quad * 4 + r;
            if (rw == lr) {
                atomicAdd(&snq[t3 * 16 + rw], sq[t3][r]);
                atomicAdd(&snk[t3 * 16 + rw], sk[t3][r]);
            }
        }
    __syncthreads();
    const int bh = bh0 + (int)bz * 4 + head;
    float* Sg = S + (long long)bh * 2304;
    for (int i = tid; i < 2304; i += 256) atomicAdd(&Sg[i], sS[i]);
    float* ng = norms + bh * 96;
    if (tid < 48) atomicAdd(&ng[tid], snq[tid]);
    else if (tid < 96) atomicAdd(&ng[tid], snk[tid - 48]);
}

__global__ __launch_bounds__(64) void softmax_k(
    const float* __restrict__ S, const float* __restrict__ norms,
    const float* __restrict__ temp, float* __restrict__ attn, int bh0)
{
    const int bh = bh0 + blockIdx.x, head = bh & 3, r = threadIdx.x;
    if (r >= 48) return;
    const float tv = temp[head];
    const float* Sg = S + (long long)bh * 2304;
    const float* ng = norms + bh * 96;
    const float nq = fmaxf(sqrtf(ng[r]), 1e-12f);
    float lg[48];
    float mx = -1e30f;
#pragma unroll
    for (int d = 0; d < 48; d++) {
        float nk = fmaxf(sqrtf(ng[48 + d]), 1e-12f);
        float v = Sg[r * 48 + d] * tv / (nq * nk);
        lg[d] = v; mx = fmaxf(mx, v);
    }
    float sum = 0.f;
#pragma unroll
    for (int d = 0; d < 48; d++) { float e = __expf(lg[d] - mx); lg[d] = e; sum += e; }
    const float inv = 1.f / sum;
    float* Ag = attn + (long long)bh * 2304 + r * 48;
#pragma unroll
    for (int d = 0; d < 48; d++) Ag[d] = lg[d] * inv;
}

// MmF[b] = W_proj . blockdiag(attn), written directly in A-fragment layout
// (96 frags/batch; frags for padded rows 192..255 are never read validly).
__global__ __launch_bounds__(256) void mproj(
    const float* __restrict__ wproj, const float* __restrict__ attn, u16* __restrict__ Mm,
    int b0)
{
    const int ob = blockIdx.x, b = b0 + blockIdx.y, tid = threadIdx.x;
    __shared__ float sA[9216];
    const float* Ab = attn + (long long)b * 9216;
    for (int i = tid; i < 9216; i += 256) sA[i] = Ab[i];
    __syncthreads();
    for (int i = tid; i < 48 * 192; i += 256) {
        int o = ob * 48 + i / 192;
        int cc = i % 192;
        int h = cc / 48, d = cc - h * 48;
        const float* wr = wproj + o * 192 + h * 48;
        const float* ar = &sA[h * 2304 + d];
        float acc = 0.f;
        for (int c = 0; c < 48; c++) acc += wr[c] * ar[c * 48];
        // frag-layout store: F = (o>>6)*24 + ((o>>4)&3)*6 + (cc>>5)
        int fi = (o >> 6) * 24 + ((o >> 4) & 3) * 6 + (cc >> 5);
        int lanei = ((cc >> 3) & 3) * 16 + (o & 15);
        Mm[(long long)b * 49152 + (long long)fi * 512 + lanei * 8 + (cc & 7)] = f2b(acc);
    }
}

extern "C" void kernel_launch(void* const* d_in, const int* in_sizes, int n_in,
                              void* d_out, int out_size, void* d_ws, size_t ws_size,
                              hipStream_t stream)
{
    const float* x     = (const float*)d_in[0];
    const float* wqkv  = (const float*)d_in[1];
    const float* wdw   = (const float*)d_in[2];
    const float* temp  = (const float*)d_in[3];
    const float* wproj = (const float*)d_in[4];
    float* out = (float*)d_out;
    char* ws = (char*)d_ws;
    const long long CHW = (long long)CD * HW;

    if (ws_size < 2097152ULL + 31457280ULL) {  // G=1 floor (proved present)
        fill_f32<<<2048, 256, 0, stream>>>(out, out_size, 100.0f);
        return;
    }
    int G = 8;
    while (G > 1 && (unsigned long long)(2097152ULL + (unsigned long long)G * 31457280ULL) > (unsigned long long)ws_size)
        G >>= 1;

    float* S      = (float*)ws;                // 32*2304 f32
    float* norms  = (float*)(ws + 294912);     // 32*96 f32
    float* attn   = (float*)(ws + 307200);     // 32*2304 f32
    u16*   MmF    = (u16*)(ws + 602112);       // 8 * 96 frags * 512 u16 = 786432 B
    u16*   wqkvF  = (u16*)(ws + 1388544);      // 240 frags * 512 u16 = 245760 B
    u16* region1  = (u16*)(ws + 2097152);      // G*2CHW bf16
    u16* qkv_pre  = region1 + (long long)G * 2 * CHW;  // G*3CHW bf16

    zerof<<<300, 256, 0, stream>>>(S, 76800);  // S + norms contiguous
    afrag_prep<<<60, 256, 0, stream>>>(wqkv, wqkvF, O3, 240);

    for (int g0 = 0; g0 < 8; g0 += G) {
        transpose_f2b<<<dim3(256, 3, G), 256, 0, stream>>>(
            x + (long long)g0 * CHW, region1, CHW, CHW);
        gemm_af<false><<<dim3(128, 5, G), 256, 0, stream>>>(
            wqkvF, region1, qkv_pre, O3, 0LL, CHW, 3LL * CHW);
        dwconv2<<<dim3(8, 384, G), 256, 0, stream>>>(
            qkv_pre, wdw, region1, 3LL * CHW, 2LL * CHW, 0);
        dwconv2<<<dim3(8, 192, G), 256, 0, stream>>>(
            qkv_pre + 2LL * CHW, wdw, qkv_pre, 3LL * CHW, 3LL * CHW, 384);
        attn_scores<<<dim3(16, 4, G), 256, 0, stream>>>(region1, S, norms, g0 * 4);
        softmax_k<<<4 * G, 64, 0, stream>>>(S, norms, temp, attn, g0 * 4);
        mproj<<<dim3(4, G), 256, 0, stream>>>(wproj, attn, MmF, g0);
        transpose_b<<<dim3(256, 3, G), 256, 0, stream>>>(
            qkv_pre, qkv_pre + CHW, 3LL * CHW, 3LL * CHW);
        gemm_af<true><<<dim3(128, 2, G), 256, 0, stream>>>(
            MmF + (long long)g0 * 49152, qkv_pre + CHW, out + (long long)g0 * CHW,
            CD, 49152LL, 3LL * CHW, CHW);
    }
}

// Round 2
// 410.206 us; speedup vs baseline: 1.0634x; 1.0634x over previous
//
#include <hip/hip_runtime.h>
#include <stdint.h>

// Channel attention (Restormer MDTA style). FP32 in/out, bf16 MFMA internals.
// R6: transposes fused into the GEMMs — transpose_f2b and transpose_b deleted.
//   gemm_tn reads B directly in [k][n] layout (row stride HW): gemm1 from x
//   (fp32, cvt_pk to bf16 during staging), gemm2 from v_post (bf16). The
//   reg-staged transpose writes the slot-swizzled LDS layout the MFMA read
//   path consumes (write slot g^(lane&3) at rows 2lane/2lane+1; read slot
//   quad^((lr>>1)&3) — same involution). One block per 128-col n-tile stages
//   B ONCE and loops all m-blocks internally (A frags L2-hot, reloaded per mb).
// Pipeline per chunk of G batches:
//   gemm_tn<f32,bf16>: qkv_pre = Wqkv . x          (M=576, nmb=5)
//   dwconv2 qk    : qkv_pre ch[0,384) -> region1 bf16
//   dwconv2 v     : qkv_pre ch[384,576) -> qkv_pre ch[0,192)
//   attn_scores   : S[bh] += q.k^T, norms += diag MFMA
//   softmax       : attn = softmax(temp * S / (|q||k|))
//   mproj         : MmF[b] = W_proj . blockdiag(attn)  (bf16, frag layout)
//   gemm_tn<bf16,f32>: out = MmF . v_post          (M=192, nmb=2)

typedef __attribute__((ext_vector_type(8))) short bf16x8;
typedef __attribute__((ext_vector_type(4))) float f32x4;
typedef __attribute__((ext_vector_type(2))) float f32x2;
typedef __attribute__((ext_vector_type(4))) unsigned int u32x4;
typedef unsigned short u16;

#define HW 16384
#define CD 192
#define O3 576
#define KD 192

__device__ __forceinline__ float b2f(u16 u) {
    union { unsigned int i; float f; } v; v.i = ((unsigned int)u) << 16; return v.f;
}
__device__ __forceinline__ u16 f2b(float f) {
    union { float f; unsigned int i; } v; v.f = f;
    return (u16)((v.i + 0x7fffu + ((v.i >> 16) & 1u)) >> 16);  // RNE
}

__global__ __launch_bounds__(256) void fill_f32(float* p, long long n, float val) {
    long long stride = (long long)gridDim.x * 256;
    for (long long i = blockIdx.x * 256LL + threadIdx.x; i < n; i += stride) p[i] = val;
}

__global__ __launch_bounds__(256) void zerof(float* p, int n) {
    int i = blockIdx.x * 256 + threadIdx.x;
    if (i < n) p[i] = 0.f;
}

// W fp32 [M][192] -> fragment-layout bf16, rows padded to NF/48*128 with zeros.
// Frag F = rwmb*24 + mt*6 + ks  (rwmb = row>>6), holds rows rwmb*64+mt*16+[0,16)
// x k ks*32+[0,32). Within frag: lane = q*16+lr, lane's 8 k at Af[F*512+lane*8].
__global__ __launch_bounds__(256) void afrag_prep(
    const float* __restrict__ W, u16* __restrict__ Af, int M, int NF)
{
    int t = blockIdx.x * 256 + threadIdx.x;
    if (t >= NF * 64) return;
    int F = t >> 6, lane = t & 63;
    int ks = F % 6, mt = (F / 6) & 3, rwmb = F / 24;
    int row = rwmb * 64 + mt * 16 + (lane & 15);
    int k0 = ks * 32 + (lane >> 4) * 8;
    u16 v[8] __attribute__((aligned(16)));
    if (row < M) {
        const float* src = W + (long long)row * KD + k0;
#pragma unroll
        for (int j = 0; j < 8; j++) v[j] = f2b(src[j]);
    } else {
#pragma unroll
        for (int j = 0; j < 8; j++) v[j] = 0;
    }
    *(bf16x8*)&Af[(long long)F * 512 + lane * 8] = *(const bf16x8*)v;
}

// C[b][m][n] = sum_k A[m][k]*B[k][n]. B read in [k][n] layout (row stride HW
// elements of SRC type), transposed+cvt into slot-swizzled LDS during staging.
// One 128-col n-tile per block; B staged ONCE; loop over nmb m-blocks of 128.
// A pre-fragged bf16 (afrag_prep layout), reloaded per m-block (L2-hot).
template <bool SRC_F32, bool OUT_F32>
__global__ __launch_bounds__(256, 2) void gemm_tn(
    const u16* __restrict__ Afrag, const void* __restrict__ Bsrc, void* __restrict__ Cv,
    int M, int nmb, long long af_bs, long long b_bs, long long c_bs)
{
    __shared__ u16 lsB[6][128 * 32];  // 48 KiB; chunk ks: [n][slot], slot s of
                                      // row n holds kslot s ^ ((n>>1)&3)
    const int tid = threadIdx.x, lane = tid & 63, wid = tid >> 6;
    const int n0 = blockIdx.x * 128;
    const long long bz = blockIdx.z;
    const int lr = lane & 15, quad = lane >> 4;
    const int wm = (wid & 1) * 64, wn = (wid >> 1) * 64;

    // ---- stage B panel: thread = kslot wid (k = wid*8+j), cols 2*lane, 2*lane+1
    {
        const int slot = wid ^ (lane & 3);  // (2*lane >>1)&3 == lane&3
        u16* dA = &lsB[0][(2 * lane) * 32 + slot * 8];
        u16* dB = &lsB[0][(2 * lane + 1) * 32 + slot * 8];
        if (SRC_F32) {
            const float* gp = (const float*)Bsrc + bz * b_bs
                            + (long long)(wid * 8) * HW + n0 + 2 * lane;
#pragma unroll
            for (int ks = 0; ks < 6; ks++) {
                f32x2 rv[8];
#pragma unroll
                for (int j = 0; j < 8; j++) rv[j] = *(const f32x2*)(gp + (long long)j * HW);
                gp += 32LL * HW;
                unsigned int lo[4], hi[4];
#pragma unroll
                for (int i = 0; i < 4; i++) {
                    float a0 = rv[2 * i][0], b0 = rv[2 * i + 1][0];
                    float a1 = rv[2 * i][1], b1 = rv[2 * i + 1][1];
                    asm("v_cvt_pk_bf16_f32 %0, %1, %2" : "=v"(lo[i]) : "v"(a0), "v"(b0));
                    asm("v_cvt_pk_bf16_f32 %0, %1, %2" : "=v"(hi[i]) : "v"(a1), "v"(b1));
                }
                *(u32x4*)(dA + ks * 4096) = (u32x4){lo[0], lo[1], lo[2], lo[3]};
                *(u32x4*)(dB + ks * 4096) = (u32x4){hi[0], hi[1], hi[2], hi[3]};
            }
        } else {
            const u16* gp = (const u16*)Bsrc + bz * b_bs
                          + (long long)(wid * 8) * HW + n0 + 2 * lane;
#pragma unroll
            for (int ks = 0; ks < 6; ks++) {
                unsigned int rv[8];
#pragma unroll
                for (int j = 0; j < 8; j++) rv[j] = *(const unsigned int*)(gp + (long long)j * HW);
                gp += 32LL * HW;
                unsigned int lo[4], hi[4];
#pragma unroll
                for (int i = 0; i < 4; i++) {
                    lo[i] = (rv[2 * i] & 0xffffu) | (rv[2 * i + 1] << 16);
                    hi[i] = (rv[2 * i] >> 16) | (rv[2 * i + 1] & 0xffff0000u);
                }
                *(u32x4*)(dA + ks * 4096) = (u32x4){lo[0], lo[1], lo[2], lo[3]};
                *(u32x4*)(dB + ks * 4096) = (u32x4){hi[0], hi[1], hi[2], hi[3]};
            }
        }
    }
    __syncthreads();  // LDS ready; content static for all m-blocks

    const int rslot = (quad ^ ((lr >> 1) & 3)) * 8;  // content kslot == quad
    for (int mb = 0; mb < nmb; ++mb) {
        bf16x8 af[4][6];
        {
            const u16* Ap = Afrag + bz * af_bs
                          + ((long long)((mb * 2 + (wid & 1)) * 24)) * 512 + lane * 8;
#pragma unroll
            for (int mt = 0; mt < 4; mt++)
#pragma unroll
                for (int ks = 0; ks < 6; ks++)
                    af[mt][ks] = *(const bf16x8*)(Ap + (mt * 6 + ks) * 512);
        }
        f32x4 acc[4][4];
#pragma unroll
        for (int i = 0; i < 4; i++)
#pragma unroll
            for (int j = 0; j < 4; j++) acc[i][j] = (f32x4){0.f, 0.f, 0.f, 0.f};
#pragma unroll
        for (int ks = 0; ks < 6; ks++) {
            bf16x8 bfv[4];
#pragma unroll
            for (int nt = 0; nt < 4; nt++)
                bfv[nt] = *(const bf16x8*)&lsB[ks][(wn + nt * 16 + lr) * 32 + rslot];
#pragma unroll
            for (int mt = 0; mt < 4; mt++)
#pragma unroll
                for (int nt = 0; nt < 4; nt++)
                    acc[mt][nt] = __builtin_amdgcn_mfma_f32_16x16x32_bf16(af[mt][ks], bfv[nt], acc[mt][nt], 0, 0, 0);
        }
        // C/D layout: col = lane&15, row = quad*4 + reg
        const int m0 = mb * 128;
#pragma unroll
        for (int mt = 0; mt < 4; mt++)
#pragma unroll
            for (int r = 0; r < 4; r++) {
                int row = m0 + wm + mt * 16 + quad * 4 + r;
                if (row < M) {
#pragma unroll
                    for (int nt = 0; nt < 4; nt++) {
                        int col = n0 + wn + nt * 16 + lr;
                        if (OUT_F32)
                            ((float*)Cv)[bz * c_bs + (long long)row * HW + col] = acc[mt][nt][r];
                        else
                            ((u16*)Cv)[bz * c_bs + (long long)row * HW + col] = f2b(acc[mt][nt][r]);
                    }
                }
            }
    }
}

// depthwise 3x3 SAME; in/out bf16, weights fp32 (weight row = wch0 + ch).
__global__ __launch_bounds__(256) void dwconv2(
    const u16* __restrict__ in, const float* __restrict__ wdw, u16* __restrict__ outp,
    long long in_bs, long long out_bs, int wch0)
{
    const int rt = blockIdx.x, ch = blockIdx.y, tid = threadIdx.x;
    const long long bz = blockIdx.z;
    const u16* ip = in + bz * in_bs + (long long)ch * HW;
    u16* op = outp + bz * out_bs + (long long)ch * HW;
    __shared__ float t[18 * 132];
    const int r0 = rt * 16;
    if (tid < 18) {
        t[tid * 132 + 0] = 0.f;   t[tid * 132 + 129] = 0.f;
        t[tid * 132 + 130] = 0.f; t[tid * 132 + 131] = 0.f;
    }
    for (int i = tid; i < 288; i += 256) {
        int rr = i >> 4, cc = (i & 15) * 8;
        int gr = r0 + rr - 1;
        float f[8];
        if (gr >= 0 && gr < 128) {
            bf16x8 v = *(const bf16x8*)(ip + gr * 128 + cc);
#pragma unroll
            for (int j = 0; j < 8; j++) f[j] = b2f((u16)v[j]);
        } else {
#pragma unroll
            for (int j = 0; j < 8; j++) f[j] = 0.f;
        }
#pragma unroll
        for (int j = 0; j < 8; j++) t[rr * 132 + 1 + cc + j] = f[j];
    }
    float w[9];
#pragma unroll
    for (int j = 0; j < 9; j++) w[j] = wdw[(wch0 + ch) * 9 + j];
    __syncthreads();
    const int rr = tid >> 4, c8 = (tid & 15) * 8;
    float o[8] = {0.f, 0.f, 0.f, 0.f, 0.f, 0.f, 0.f, 0.f};
#pragma unroll
    for (int dy = 0; dy < 3; dy++) {
        const float* row = &t[(rr + dy) * 132 + c8];  // LDS idx c8 == image col c8-1
        float r[12] __attribute__((aligned(16)));
        *(f32x4*)&r[0] = *(const f32x4*)row;
        *(f32x4*)&r[4] = *(const f32x4*)(row + 4);
        *(f32x4*)&r[8] = *(const f32x4*)(row + 8);
        const float w0 = w[dy * 3], w1 = w[dy * 3 + 1], w2 = w[dy * 3 + 2];
#pragma unroll
        for (int j = 0; j < 8; j++) o[j] += w0 * r[j] + w1 * r[j + 1] + w2 * r[j + 2];
    }
    u16 ob[8] __attribute__((aligned(16)));
#pragma unroll
    for (int j = 0; j < 8; j++) ob[j] = f2b(o[j]);
    *(bf16x8*)&op[(long long)(r0 + rr) * 128 + c8] = *(const bf16x8*)ob;
}

// S[bh][48][48] += q.k^T ; norms[bh][96] += diag(q.q^T), diag(k.k^T)
__global__ __launch_bounds__(256) void attn_scores(
    const u16* __restrict__ qk, float* __restrict__ S, float* __restrict__ norms,
    int bh0)
{
    const int tid = threadIdx.x, lane = tid & 63, wid = tid >> 6;
    const int kc = blockIdx.x, head = blockIdx.y;
    const long long bz = blockIdx.z;
    const u16* q = qk + bz * (2LL * CD * HW) + (long long)head * 48 * HW;
    const u16* k = q + (long long)CD * HW;
    const int lr = lane & 15, quad = lane >> 4;

    f32x4 sc[3][3], sq[3], sk[3];
#pragma unroll
    for (int i = 0; i < 3; i++) {
#pragma unroll
        for (int j = 0; j < 3; j++) sc[i][j] = (f32x4){0.f, 0.f, 0.f, 0.f};
        sq[i] = (f32x4){0.f, 0.f, 0.f, 0.f};
        sk[i] = (f32x4){0.f, 0.f, 0.f, 0.f};
    }
    const int n0 = kc * 1024 + wid * 256;
#pragma unroll 2
    for (int s = 0; s < 8; s++) {
        const int n = n0 + s * 32 + quad * 8;
        bf16x8 aq[3], ak[3];
#pragma unroll
        for (int t3 = 0; t3 < 3; t3++) {
            aq[t3] = *(const bf16x8*)(q + (long long)(t3 * 16 + lr) * HW + n);
            ak[t3] = *(const bf16x8*)(k + (long long)(t3 * 16 + lr) * HW + n);
        }
#pragma unroll
        for (int mt = 0; mt < 3; mt++)
#pragma unroll
            for (int nt = 0; nt < 3; nt++)
                sc[mt][nt] = __builtin_amdgcn_mfma_f32_16x16x32_bf16(aq[mt], ak[nt], sc[mt][nt], 0, 0, 0);
#pragma unroll
        for (int t3 = 0; t3 < 3; t3++) {
            sq[t3] = __builtin_amdgcn_mfma_f32_16x16x32_bf16(aq[t3], aq[t3], sq[t3], 0, 0, 0);
            sk[t3] = __builtin_amdgcn_mfma_f32_16x16x32_bf16(ak[t3], ak[t3], sk[t3], 0, 0, 0);
        }
    }
    __shared__ float sS[2304];
    __shared__ float snq[48], snk[48];
    for (int i = tid; i < 2304; i += 256) sS[i] = 0.f;
    if (tid < 48) { snq[tid] = 0.f; snk[tid] = 0.f; }
    __syncthreads();
#pragma unroll
    for (int mt = 0; mt < 3; mt++)
#pragma unroll
        for (int nt = 0; nt < 3; nt++)
#pragma unroll
            for (int r = 0; r < 4; r++)
                atomicAdd(&sS[(mt * 16 + quad * 4 + r) * 48 + nt * 16 + lr], sc[mt][nt][r]);
#pragma unroll
    for (int t3 = 0; t3 < 3; t3++)
#pragma unroll
        for (int r = 0; r < 4; r++) {
            int rw = quad * 4 + r;
            if (rw == lr) {
                atomicAdd(&snq[t3 * 16 + rw], sq[t3][r]);
                atomicAdd(&snk[t3 * 16 + rw], sk[t3][r]);
            }
        }
    __syncthreads();
    const int bh = bh0 + (int)bz * 4 + head;
    float* Sg = S + (long long)bh * 2304;
    for (int i = tid; i < 2304; i += 256) atomicAdd(&Sg[i], sS[i]);
    float* ng = norms + bh * 96;
    if (tid < 48) atomicAdd(&ng[tid], snq[tid]);
    else if (tid < 96) atomicAdd(&ng[tid], snk[tid - 48]);
}

__global__ __launch_bounds__(64) void softmax_k(
    const float* __restrict__ S, const float* __restrict__ norms,
    const float* __restrict__ temp, float* __restrict__ attn, int bh0)
{
    const int bh = bh0 + blockIdx.x, head = bh & 3, r = threadIdx.x;
    if (r >= 48) return;
    const float tv = temp[head];
    const float* Sg = S + (long long)bh * 2304;
    const float* ng = norms + bh * 96;
    const float nq = fmaxf(sqrtf(ng[r]), 1e-12f);
    float lg[48];
    float mx = -1e30f;
#pragma unroll
    for (int d = 0; d < 48; d++) {
        float nk = fmaxf(sqrtf(ng[48 + d]), 1e-12f);
        float v = Sg[r * 48 + d] * tv / (nq * nk);
        lg[d] = v; mx = fmaxf(mx, v);
    }
    float sum = 0.f;
#pragma unroll
    for (int d = 0; d < 48; d++) { float e = __expf(lg[d] - mx); lg[d] = e; sum += e; }
    const float inv = 1.f / sum;
    float* Ag = attn + (long long)bh * 2304 + r * 48;
#pragma unroll
    for (int d = 0; d < 48; d++) Ag[d] = lg[d] * inv;
}

// MmF[b] = W_proj . blockdiag(attn), written directly in A-fragment layout.
__global__ __launch_bounds__(256) void mproj(
    const float* __restrict__ wproj, const float* __restrict__ attn, u16* __restrict__ Mm,
    int b0)
{
    const int ob = blockIdx.x, b = b0 + blockIdx.y, tid = threadIdx.x;
    __shared__ float sA[9216];
    const float* Ab = attn + (long long)b * 9216;
    for (int i = tid; i < 9216; i += 256) sA[i] = Ab[i];
    __syncthreads();
    for (int i = tid; i < 48 * 192; i += 256) {
        int o = ob * 48 + i / 192;
        int cc = i % 192;
        int h = cc / 48, d = cc - h * 48;
        const float* wr = wproj + o * 192 + h * 48;
        const float* ar = &sA[h * 2304 + d];
        float acc = 0.f;
        for (int c = 0; c < 48; c++) acc += wr[c] * ar[c * 48];
        // frag-layout store: F = (o>>6)*24 + ((o>>4)&3)*6 + (cc>>5)
        int fi = (o >> 6) * 24 + ((o >> 4) & 3) * 6 + (cc >> 5);
        int lanei = ((cc >> 3) & 3) * 16 + (o & 15);
        Mm[(long long)b * 49152 + (long long)fi * 512 + lanei * 8 + (cc & 7)] = f2b(acc);
    }
}

extern "C" void kernel_launch(void* const* d_in, const int* in_sizes, int n_in,
                              void* d_out, int out_size, void* d_ws, size_t ws_size,
                              hipStream_t stream)
{
    const float* x     = (const float*)d_in[0];
    const float* wqkv  = (const float*)d_in[1];
    const float* wdw   = (const float*)d_in[2];
    const float* temp  = (const float*)d_in[3];
    const float* wproj = (const float*)d_in[4];
    float* out = (float*)d_out;
    char* ws = (char*)d_ws;
    const long long CHW = (long long)CD * HW;

    if (ws_size < 2097152ULL + 31457280ULL) {  // G=1 floor (proved present)
        fill_f32<<<2048, 256, 0, stream>>>(out, out_size, 100.0f);
        return;
    }
    int G = 8;
    while (G > 1 && (unsigned long long)(2097152ULL + (unsigned long long)G * 31457280ULL) > (unsigned long long)ws_size)
        G >>= 1;

    float* S      = (float*)ws;                // 32*2304 f32
    float* norms  = (float*)(ws + 294912);     // 32*96 f32
    float* attn   = (float*)(ws + 307200);     // 32*2304 f32
    u16*   MmF    = (u16*)(ws + 602112);       // 8 * 96 frags * 512 u16
    u16*   wqkvF  = (u16*)(ws + 1388544);      // 240 frags * 512 u16
    u16* region1  = (u16*)(ws + 2097152);      // G*2CHW bf16 (qk_post)
    u16* qkv_pre  = region1 + (long long)G * 2 * CHW;  // G*3CHW bf16

    zerof<<<300, 256, 0, stream>>>(S, 76800);  // S + norms contiguous
    afrag_prep<<<60, 256, 0, stream>>>(wqkv, wqkvF, O3, 240);

    for (int g0 = 0; g0 < 8; g0 += G) {
        // qkv_pre = Wqkv . x  (B = x fp32 [c][p], transposed+cvt in staging)
        gemm_tn<true, false><<<dim3(128, 1, G), 256, 0, stream>>>(
            wqkvF, x + (long long)g0 * CHW, qkv_pre, O3, 5, 0LL, CHW, 3LL * CHW);
        dwconv2<<<dim3(8, 384, G), 256, 0, stream>>>(
            qkv_pre, wdw, region1, 3LL * CHW, 2LL * CHW, 0);
        dwconv2<<<dim3(8, 192, G), 256, 0, stream>>>(
            qkv_pre + 2LL * CHW, wdw, qkv_pre, 3LL * CHW, 3LL * CHW, 384);
        attn_scores<<<dim3(16, 4, G), 256, 0, stream>>>(region1, S, norms, g0 * 4);
        softmax_k<<<4 * G, 64, 0, stream>>>(S, norms, temp, attn, g0 * 4);
        mproj<<<dim3(4, G), 256, 0, stream>>>(wproj, attn, MmF, g0);
        // out = MmF . v_post  (B = qkv_pre ch[0,192) bf16 [c][p])
        gemm_tn<false, true><<<dim3(128, 1, G), 256, 0, stream>>>(
            MmF + (long long)g0 * 49152, qkv_pre, out + (long long)g0 * CHW,
            CD, 2, 49152LL, 3LL * CHW, CHW);
    }
}

// Round 3
// 408.078 us; speedup vs baseline: 1.0689x; 1.0052x over previous
//
#include <hip/hip_runtime.h>
#include <stdint.h>

// Channel attention (Restormer MDTA style). FP32 in/out, bf16 MFMA internals.
// R7: gemm_tn re-parallelized — R6's 128-col/48KB/2-blocks-per-CU structure was
//   latency-bound (88us @ 2.3TB/s, all counters low). Now: 64-col n-tiles
//   (24KB LDS), 2048 blocks, 4 waves split along M (2 mt each, acc=32 regs,
//   af[2][6]=48 regs held), staging loads fully preloaded into distinct regs
//   (one vmcnt drain instead of 6 serialized HBM round trips), NMB template-
//   unrolled. Same slot-XOR swizzle involution as R6 (write slot kslot^((n>>1)&3),
//   read slot quad^((lr>>1)&3)); same frag conventions.
// Pipeline per chunk of G batches:
//   gemm_tn<f32,bf16,5>: qkv_pre = Wqkv . x        (M=576)
//   dwconv2 qk    : qkv_pre ch[0,384) -> region1 bf16
//   dwconv2 v     : qkv_pre ch[384,576) -> qkv_pre ch[0,192)
//   attn_scores   : S[bh] += q.k^T, norms += diag MFMA
//   softmax       : attn = softmax(temp * S / (|q||k|))
//   mproj         : MmF[b] = W_proj . blockdiag(attn)  (bf16, frag layout)
//   gemm_tn<bf16,f32,2>: out = MmF . v_post        (M=192)

typedef __attribute__((ext_vector_type(8))) short bf16x8;
typedef __attribute__((ext_vector_type(4))) float f32x4;
typedef __attribute__((ext_vector_type(2))) float f32x2;
typedef __attribute__((ext_vector_type(4))) unsigned int u32x4;
typedef unsigned short u16;

#define HW 16384
#define CD 192
#define O3 576
#define KD 192

__device__ __forceinline__ float b2f(u16 u) {
    union { unsigned int i; float f; } v; v.i = ((unsigned int)u) << 16; return v.f;
}
__device__ __forceinline__ u16 f2b(float f) {
    union { float f; unsigned int i; } v; v.f = f;
    return (u16)((v.i + 0x7fffu + ((v.i >> 16) & 1u)) >> 16);  // RNE
}

__global__ __launch_bounds__(256) void fill_f32(float* p, long long n, float val) {
    long long stride = (long long)gridDim.x * 256;
    for (long long i = blockIdx.x * 256LL + threadIdx.x; i < n; i += stride) p[i] = val;
}

__global__ __launch_bounds__(256) void zerof(float* p, int n) {
    int i = blockIdx.x * 256 + threadIdx.x;
    if (i < n) p[i] = 0.f;
}

// W fp32 [M][192] -> fragment-layout bf16, rows padded to NF/48*128 with zeros.
// Frag F = rwmb*24 + mt*6 + ks  (rwmb = row>>6), holds rows rwmb*64+mt*16+[0,16)
// x k ks*32+[0,32). Within frag: lane = q*16+lr, lane's 8 k at Af[F*512+lane*8].
__global__ __launch_bounds__(256) void afrag_prep(
    const float* __restrict__ W, u16* __restrict__ Af, int M, int NF)
{
    int t = blockIdx.x * 256 + threadIdx.x;
    if (t >= NF * 64) return;
    int F = t >> 6, lane = t & 63;
    int ks = F % 6, mt = (F / 6) & 3, rwmb = F / 24;
    int row = rwmb * 64 + mt * 16 + (lane & 15);
    int k0 = ks * 32 + (lane >> 4) * 8;
    u16 v[8] __attribute__((aligned(16)));
    if (row < M) {
        const float* src = W + (long long)row * KD + k0;
#pragma unroll
        for (int j = 0; j < 8; j++) v[j] = f2b(src[j]);
    } else {
#pragma unroll
        for (int j = 0; j < 8; j++) v[j] = 0;
    }
    *(bf16x8*)&Af[(long long)F * 512 + lane * 8] = *(const bf16x8*)v;
}

// C[b][m][n] = sum_k A[m][k]*B[k][n]. B read in [k][n] layout (row stride HW),
// transposed+cvt into slot-swizzled LDS during staging (all loads preloaded
// into distinct regs -> one latency exposure). 64-col n-tile per block;
// 4 waves split M (32 rows each); NMB m-blocks of 128, unrolled.
template <bool SRC_F32, bool OUT_F32, int NMB>
__global__ __launch_bounds__(256, 2) void gemm_tn(
    const u16* __restrict__ Afrag, const void* __restrict__ Bsrc, void* __restrict__ Cv,
    int M, long long af_bs, long long b_bs, long long c_bs)
{
    __shared__ u16 lsB[6][64 * 32];  // 24 KiB; chunk ks: [n][slot], slot s of
                                     // row n holds kslot s ^ ((n>>1)&3)
    const int tid = threadIdx.x, lane = tid & 63, wid = tid >> 6;
    const int n0 = blockIdx.x * 64;
    const long long bz = blockIdx.z;
    const int lr = lane & 15, quad = lane >> 4;

    // ---- stage B panel (192k x 64n): thread (kg,l5) covers k=r*64+kg*8+j,
    //      cols 2*l5, 2*l5+1.  All 24 loads preloaded, then convert+write.
    {
        const int kg = tid >> 5, l5 = tid & 31;
        const int slot = (kg & 3) ^ (l5 & 3);
        u16* dA = &lsB[0][(2 * l5) * 32 + slot * 8];  // +ck*2048 elems per chunk
        if (SRC_F32) {
            const float* gp = (const float*)Bsrc + bz * b_bs
                            + (long long)(kg * 8) * HW + n0 + 2 * l5;
            f32x2 rv[24];
#pragma unroll
            for (int r = 0; r < 3; r++)
#pragma unroll
                for (int j = 0; j < 8; j++)
                    rv[r * 8 + j] = *(const f32x2*)(gp + ((long long)r * 64 + j) * HW);
#pragma unroll
            for (int r = 0; r < 3; r++) {
                unsigned int lo[4], hi[4];
#pragma unroll
                for (int i = 0; i < 4; i++) {
                    float a0 = rv[r * 8 + 2 * i][0], b0 = rv[r * 8 + 2 * i + 1][0];
                    float a1 = rv[r * 8 + 2 * i][1], b1 = rv[r * 8 + 2 * i + 1][1];
                    asm("v_cvt_pk_bf16_f32 %0, %1, %2" : "=v"(lo[i]) : "v"(a0), "v"(b0));
                    asm("v_cvt_pk_bf16_f32 %0, %1, %2" : "=v"(hi[i]) : "v"(a1), "v"(b1));
                }
                const int ck = r * 2 + (kg >> 2);
                *(u32x4*)(dA + ck * 2048)      = (u32x4){lo[0], lo[1], lo[2], lo[3]};
                *(u32x4*)(dA + ck * 2048 + 32) = (u32x4){hi[0], hi[1], hi[2], hi[3]};
            }
        } else {
            const u16* gp = (const u16*)Bsrc + bz * b_bs
                          + (long long)(kg * 8) * HW + n0 + 2 * l5;
            unsigned int rv[24];
#pragma unroll
            for (int r = 0; r < 3; r++)
#pragma unroll
                for (int j = 0; j < 8; j++)
                    rv[r * 8 + j] = *(const unsigned int*)(gp + ((long long)r * 64 + j) * HW);
#pragma unroll
            for (int r = 0; r < 3; r++) {
                unsigned int lo[4], hi[4];
#pragma unroll
                for (int i = 0; i < 4; i++) {
                    unsigned int e = rv[r * 8 + 2 * i], o = rv[r * 8 + 2 * i + 1];
                    lo[i] = (e & 0xffffu) | (o << 16);
                    hi[i] = (e >> 16) | (o & 0xffff0000u);
                }
                const int ck = r * 2 + (kg >> 2);
                *(u32x4*)(dA + ck * 2048)      = (u32x4){lo[0], lo[1], lo[2], lo[3]};
                *(u32x4*)(dA + ck * 2048 + 32) = (u32x4){hi[0], hi[1], hi[2], hi[3]};
            }
        }
    }
    __syncthreads();  // LDS ready; content static for all m-blocks

    const int rslot = (quad ^ ((lr >> 1) & 3)) * 8;  // content kslot == quad
#pragma unroll
    for (int mb = 0; mb < NMB; ++mb) {
        const int wmBase = mb * 128 + wid * 32;
        if (wmBase >= M) continue;  // whole wave masked (gemm2 tail)
        // A frags for this wave's 32 rows (held: 48 VGPRs)
        bf16x8 af[2][6];
        {
            const u16* Ap = Afrag + bz * af_bs
                          + ((long long)((mb * 2 + (wid >> 1)) * 24)) * 512 + lane * 8;
#pragma unroll
            for (int mtl = 0; mtl < 2; mtl++)
#pragma unroll
                for (int ks = 0; ks < 6; ks++)
                    af[mtl][ks] = *(const bf16x8*)(Ap + (((wid & 1) * 2 + mtl) * 6 + ks) * 512);
        }
        f32x4 acc[2][4];
#pragma unroll
        for (int i = 0; i < 2; i++)
#pragma unroll
            for (int j = 0; j < 4; j++) acc[i][j] = (f32x4){0.f, 0.f, 0.f, 0.f};
#pragma unroll
        for (int ks = 0; ks < 6; ks++) {
            bf16x8 bfv[4];
#pragma unroll
            for (int nt = 0; nt < 4; nt++)
                bfv[nt] = *(const bf16x8*)&lsB[ks][(nt * 16 + lr) * 32 + rslot];
#pragma unroll
            for (int mtl = 0; mtl < 2; mtl++)
#pragma unroll
                for (int nt = 0; nt < 4; nt++)
                    acc[mtl][nt] = __builtin_amdgcn_mfma_f32_16x16x32_bf16(af[mtl][ks], bfv[nt], acc[mtl][nt], 0, 0, 0);
        }
        // C/D layout: col = lane&15, row = quad*4 + reg
#pragma unroll
        for (int mtl = 0; mtl < 2; mtl++)
#pragma unroll
            for (int r = 0; r < 4; r++) {
                int row = wmBase + mtl * 16 + quad * 4 + r;
                if (row < M) {
#pragma unroll
                    for (int nt = 0; nt < 4; nt++) {
                        int col = n0 + nt * 16 + lr;
                        if (OUT_F32)
                            ((float*)Cv)[bz * c_bs + (long long)row * HW + col] = acc[mtl][nt][r];
                        else
                            ((u16*)Cv)[bz * c_bs + (long long)row * HW + col] = f2b(acc[mtl][nt][r]);
                    }
                }
            }
    }
}

// depthwise 3x3 SAME; in/out bf16, weights fp32 (weight row = wch0 + ch).
__global__ __launch_bounds__(256) void dwconv2(
    const u16* __restrict__ in, const float* __restrict__ wdw, u16* __restrict__ outp,
    long long in_bs, long long out_bs, int wch0)
{
    const int rt = blockIdx.x, ch = blockIdx.y, tid = threadIdx.x;
    const long long bz = blockIdx.z;
    const u16* ip = in + bz * in_bs + (long long)ch * HW;
    u16* op = outp + bz * out_bs + (long long)ch * HW;
    __shared__ float t[18 * 132];
    const int r0 = rt * 16;
    if (tid < 18) {
        t[tid * 132 + 0] = 0.f;   t[tid * 132 + 129] = 0.f;
        t[tid * 132 + 130] = 0.f; t[tid * 132 + 131] = 0.f;
    }
    for (int i = tid; i < 288; i += 256) {
        int rr = i >> 4, cc = (i & 15) * 8;
        int gr = r0 + rr - 1;
        float f[8];
        if (gr >= 0 && gr < 128) {
            bf16x8 v = *(const bf16x8*)(ip + gr * 128 + cc);
#pragma unroll
            for (int j = 0; j < 8; j++) f[j] = b2f((u16)v[j]);
        } else {
#pragma unroll
            for (int j = 0; j < 8; j++) f[j] = 0.f;
        }
#pragma unroll
        for (int j = 0; j < 8; j++) t[rr * 132 + 1 + cc + j] = f[j];
    }
    float w[9];
#pragma unroll
    for (int j = 0; j < 9; j++) w[j] = wdw[(wch0 + ch) * 9 + j];
    __syncthreads();
    const int rr = tid >> 4, c8 = (tid & 15) * 8;
    float o[8] = {0.f, 0.f, 0.f, 0.f, 0.f, 0.f, 0.f, 0.f};
#pragma unroll
    for (int dy = 0; dy < 3; dy++) {
        const float* row = &t[(rr + dy) * 132 + c8];  // LDS idx c8 == image col c8-1
        float r[12] __attribute__((aligned(16)));
        *(f32x4*)&r[0] = *(const f32x4*)row;
        *(f32x4*)&r[4] = *(const f32x4*)(row + 4);
        *(f32x4*)&r[8] = *(const f32x4*)(row + 8);
        const float w0 = w[dy * 3], w1 = w[dy * 3 + 1], w2 = w[dy * 3 + 2];
#pragma unroll
        for (int j = 0; j < 8; j++) o[j] += w0 * r[j] + w1 * r[j + 1] + w2 * r[j + 2];
    }
    u16 ob[8] __attribute__((aligned(16)));
#pragma unroll
    for (int j = 0; j < 8; j++) ob[j] = f2b(o[j]);
    *(bf16x8*)&op[(long long)(r0 + rr) * 128 + c8] = *(const bf16x8*)ob;
}

// S[bh][48][48] += q.k^T ; norms[bh][96] += diag(q.q^T), diag(k.k^T)
__global__ __launch_bounds__(256) void attn_scores(
    const u16* __restrict__ qk, float* __restrict__ S, float* __restrict__ norms,
    int bh0)
{
    const int tid = threadIdx.x, lane = tid & 63, wid = tid >> 6;
    const int kc = blockIdx.x, head = blockIdx.y;
    const long long bz = blockIdx.z;
    const u16* q = qk + bz * (2LL * CD * HW) + (long long)head * 48 * HW;
    const u16* k = q + (long long)CD * HW;
    const int lr = lane & 15, quad = lane >> 4;

    f32x4 sc[3][3], sq[3], sk[3];
#pragma unroll
    for (int i = 0; i < 3; i++) {
#pragma unroll
        for (int j = 0; j < 3; j++) sc[i][j] = (f32x4){0.f, 0.f, 0.f, 0.f};
        sq[i] = (f32x4){0.f, 0.f, 0.f, 0.f};
        sk[i] = (f32x4){0.f, 0.f, 0.f, 0.f};
    }
    const int n0 = kc * 1024 + wid * 256;
#pragma unroll 2
    for (int s = 0; s < 8; s++) {
        const int n = n0 + s * 32 + quad * 8;
        bf16x8 aq[3], ak[3];
#pragma unroll
        for (int t3 = 0; t3 < 3; t3++) {
            aq[t3] = *(const bf16x8*)(q + (long long)(t3 * 16 + lr) * HW + n);
            ak[t3] = *(const bf16x8*)(k + (long long)(t3 * 16 + lr) * HW + n);
        }
#pragma unroll
        for (int mt = 0; mt < 3; mt++)
#pragma unroll
            for (int nt = 0; nt < 3; nt++)
                sc[mt][nt] = __builtin_amdgcn_mfma_f32_16x16x32_bf16(aq[mt], ak[nt], sc[mt][nt], 0, 0, 0);
#pragma unroll
        for (int t3 = 0; t3 < 3; t3++) {
            sq[t3] = __builtin_amdgcn_mfma_f32_16x16x32_bf16(aq[t3], aq[t3], sq[t3], 0, 0, 0);
            sk[t3] = __builtin_amdgcn_mfma_f32_16x16x32_bf16(ak[t3], ak[t3], sk[t3], 0, 0, 0);
        }
    }
    __shared__ float sS[2304];
    __shared__ float snq[48], snk[48];
    for (int i = tid; i < 2304; i += 256) sS[i] = 0.f;
    if (tid < 48) { snq[tid] = 0.f; snk[tid] = 0.f; }
    __syncthreads();
#pragma unroll
    for (int mt = 0; mt < 3; mt++)
#pragma unroll
        for (int nt = 0; nt < 3; nt++)
#pragma unroll
            for (int r = 0; r < 4; r++)
                atomicAdd(&sS[(mt * 16 + quad * 4 + r) * 48 + nt * 16 + lr], sc[mt][nt][r]);
#pragma unroll
    for (int t3 = 0; t3 < 3; t3++)
#pragma unroll
        for (int r = 0; r < 4; r++) {
            int rw = quad * 4 + r;
            if (rw == lr) {
                atomicAdd(&snq[t3 * 16 + rw], sq[t3][r]);
                atomicAdd(&snk[t3 * 16 + rw], sk[t3][r]);
            }
        }
    __syncthreads();
    const int bh = bh0 + (int)bz * 4 + head;
    float* Sg = S + (long long)bh * 2304;
    for (int i = tid; i < 2304; i += 256) atomicAdd(&Sg[i], sS[i]);
    float* ng = norms + bh * 96;
    if (tid < 48) atomicAdd(&ng[tid], snq[tid]);
    else if (tid < 96) atomicAdd(&ng[tid], snk[tid - 48]);
}

__global__ __launch_bounds__(64) void softmax_k(
    const float* __restrict__ S, const float* __restrict__ norms,
    const float* __restrict__ temp, float* __restrict__ attn, int bh0)
{
    const int bh = bh0 + blockIdx.x, head = bh & 3, r = threadIdx.x;
    if (r >= 48) return;
    const float tv = temp[head];
    const float* Sg = S + (long long)bh * 2304;
    const float* ng = norms + bh * 96;
    const float nq = fmaxf(sqrtf(ng[r]), 1e-12f);
    float lg[48];
    float mx = -1e30f;
#pragma unroll
    for (int d = 0; d < 48; d++) {
        float nk = fmaxf(sqrtf(ng[48 + d]), 1e-12f);
        float v = Sg[r * 48 + d] * tv / (nq * nk);
        lg[d] = v; mx = fmaxf(mx, v);
    }
    float sum = 0.f;
#pragma unroll
    for (int d = 0; d < 48; d++) { float e = __expf(lg[d] - mx); lg[d] = e; sum += e; }
    const float inv = 1.f / sum;
    float* Ag = attn + (long long)bh * 2304 + r * 48;
#pragma unroll
    for (int d = 0; d < 48; d++) Ag[d] = lg[d] * inv;
}

// MmF[b] = W_proj . blockdiag(attn), written directly in A-fragment layout.
__global__ __launch_bounds__(256) void mproj(
    const float* __restrict__ wproj, const float* __restrict__ attn, u16* __restrict__ Mm,
    int b0)
{
    const int ob = blockIdx.x, b = b0 + blockIdx.y, tid = threadIdx.x;
    __shared__ float sA[9216];
    const float* Ab = attn + (long long)b * 9216;
    for (int i = tid; i < 9216; i += 256) sA[i] = Ab[i];
    __syncthreads();
    for (int i = tid; i < 48 * 192; i += 256) {
        int o = ob * 48 + i / 192;
        int cc = i % 192;
        int h = cc / 48, d = cc - h * 48;
        const float* wr = wproj + o * 192 + h * 48;
        const float* ar = &sA[h * 2304 + d];
        float acc = 0.f;
        for (int c = 0; c < 48; c++) acc += wr[c] * ar[c * 48];
        // frag-layout store: F = (o>>6)*24 + ((o>>4)&3)*6 + (cc>>5)
        int fi = (o >> 6) * 24 + ((o >> 4) & 3) * 6 + (cc >> 5);
        int lanei = ((cc >> 3) & 3) * 16 + (o & 15);
        Mm[(long long)b * 49152 + (long long)fi * 512 + lanei * 8 + (cc & 7)] = f2b(acc);
    }
}

extern "C" void kernel_launch(void* const* d_in, const int* in_sizes, int n_in,
                              void* d_out, int out_size, void* d_ws, size_t ws_size,
                              hipStream_t stream)
{
    const float* x     = (const float*)d_in[0];
    const float* wqkv  = (const float*)d_in[1];
    const float* wdw   = (const float*)d_in[2];
    const float* temp  = (const float*)d_in[3];
    const float* wproj = (const float*)d_in[4];
    float* out = (float*)d_out;
    char* ws = (char*)d_ws;
    const long long CHW = (long long)CD * HW;

    if (ws_size < 2097152ULL + 31457280ULL) {  // G=1 floor (proved present)
        fill_f32<<<2048, 256, 0, stream>>>(out, out_size, 100.0f);
        return;
    }
    int G = 8;
    while (G > 1 && (unsigned long long)(2097152ULL + (unsigned long long)G * 31457280ULL) > (unsigned long long)ws_size)
        G >>= 1;

    float* S      = (float*)ws;                // 32*2304 f32
    float* norms  = (float*)(ws + 294912);     // 32*96 f32
    float* attn   = (float*)(ws + 307200);     // 32*2304 f32
    u16*   MmF    = (u16*)(ws + 602112);       // 8 * 96 frags * 512 u16
    u16*   wqkvF  = (u16*)(ws + 1388544);      // 240 frags * 512 u16
    u16* region1  = (u16*)(ws + 2097152);      // G*2CHW bf16 (qk_post)
    u16* qkv_pre  = region1 + (long long)G * 2 * CHW;  // G*3CHW bf16

    zerof<<<300, 256, 0, stream>>>(S, 76800);  // S + norms contiguous
    afrag_prep<<<60, 256, 0, stream>>>(wqkv, wqkvF, O3, 240);

    for (int g0 = 0; g0 < 8; g0 += G) {
        // qkv_pre = Wqkv . x  (B = x fp32 [c][p], transposed+cvt in staging)
        gemm_tn<true, false, 5><<<dim3(256, 1, G), 256, 0, stream>>>(
            wqkvF, x + (long long)g0 * CHW, qkv_pre, O3, 0LL, CHW, 3LL * CHW);
        dwconv2<<<dim3(8, 384, G), 256, 0, stream>>>(
            qkv_pre, wdw, region1, 3LL * CHW, 2LL * CHW, 0);
        dwconv2<<<dim3(8, 192, G), 256, 0, stream>>>(
            qkv_pre + 2LL * CHW, wdw, qkv_pre, 3LL * CHW, 3LL * CHW, 384);
        attn_scores<<<dim3(16, 4, G), 256, 0, stream>>>(region1, S, norms, g0 * 4);
        softmax_k<<<4 * G, 64, 0, stream>>>(S, norms, temp, attn, g0 * 4);
        mproj<<<dim3(4, G), 256, 0, stream>>>(wproj, attn, MmF, g0);
        // out = MmF . v_post  (B = qkv_pre ch[0,192) bf16 [c][p])
        gemm_tn<false, true, 2><<<dim3(256, 1, G), 256, 0, stream>>>(
            MmF + (long long)g0 * 49152, qkv_pre, out + (long long)g0 * CHW,
            CD, 49152LL, 3LL * CHW, CHW);
    }
}

// Round 4
// 405.586 us; speedup vs baseline: 1.0755x; 1.0061x over previous
//
#include <hip/hip_runtime.h>
#include <stdint.h>

// Channel attention (Restormer MDTA style). FP32 in/out, bf16 MFMA internals.
// R8: gemm_tn register-residency made structural — R7's VGPR_Count=40 showed
//   the compiler serialized af reloads + per-mb LDS rereads (MfmaUtil 11%).
//   Now: B-frags hoisted to regs ONCE after sync (bfv[6][4], 96 VGPR; LDS dead
//   afterwards); A-frags double-buffered af0/af1 with prefetch of mb+1 issued
//   before mb's 48 MFMAs (L2 latency hidden under MFMA); mb loop template-
//   unrolled so all buffer indexing is compile-time; af0 loads issued before
//   __syncthreads to overlap the staging drain; per-row store bounds dropped
//   (M multiple of 32 -> wave-level mask suffices). ~240 VGPR under (256,2).
//   Staging/swizzle identical to R7 (verified involution).
// Pipeline per chunk of G batches:
//   gemm_tn<f32,bf16,5>: qkv_pre = Wqkv . x        (M=576)
//   dwconv2 qk    : qkv_pre ch[0,384) -> region1 bf16
//   dwconv2 v     : qkv_pre ch[384,576) -> qkv_pre ch[0,192)
//   attn_scores   : S[bh] += q.k^T, norms += diag MFMA
//   softmax       : attn = softmax(temp * S / (|q||k|))
//   mproj         : MmF[b] = W_proj . blockdiag(attn)  (bf16, frag layout)
//   gemm_tn<bf16,f32,2>: out = MmF . v_post        (M=192)

typedef __attribute__((ext_vector_type(8))) short bf16x8;
typedef __attribute__((ext_vector_type(4))) float f32x4;
typedef __attribute__((ext_vector_type(2))) float f32x2;
typedef __attribute__((ext_vector_type(4))) unsigned int u32x4;
typedef unsigned short u16;

#define HW 16384
#define CD 192
#define O3 576
#define KD 192

__device__ __forceinline__ float b2f(u16 u) {
    union { unsigned int i; float f; } v; v.i = ((unsigned int)u) << 16; return v.f;
}
__device__ __forceinline__ u16 f2b(float f) {
    union { float f; unsigned int i; } v; v.f = f;
    return (u16)((v.i + 0x7fffu + ((v.i >> 16) & 1u)) >> 16);  // RNE
}

__global__ __launch_bounds__(256) void fill_f32(float* p, long long n, float val) {
    long long stride = (long long)gridDim.x * 256;
    for (long long i = blockIdx.x * 256LL + threadIdx.x; i < n; i += stride) p[i] = val;
}

__global__ __launch_bounds__(256) void zerof(float* p, int n) {
    int i = blockIdx.x * 256 + threadIdx.x;
    if (i < n) p[i] = 0.f;
}

// W fp32 [M][192] -> fragment-layout bf16, rows padded to NF/48*128 with zeros.
// Frag F = rwmb*24 + mt*6 + ks  (rwmb = row>>6), holds rows rwmb*64+mt*16+[0,16)
// x k ks*32+[0,32). Within frag: lane = q*16+lr, lane's 8 k at Af[F*512+lane*8].
__global__ __launch_bounds__(256) void afrag_prep(
    const float* __restrict__ W, u16* __restrict__ Af, int M, int NF)
{
    int t = blockIdx.x * 256 + threadIdx.x;
    if (t >= NF * 64) return;
    int F = t >> 6, lane = t & 63;
    int ks = F % 6, mt = (F / 6) & 3, rwmb = F / 24;
    int row = rwmb * 64 + mt * 16 + (lane & 15);
    int k0 = ks * 32 + (lane >> 4) * 8;
    u16 v[8] __attribute__((aligned(16)));
    if (row < M) {
        const float* src = W + (long long)row * KD + k0;
#pragma unroll
        for (int j = 0; j < 8; j++) v[j] = f2b(src[j]);
    } else {
#pragma unroll
        for (int j = 0; j < 8; j++) v[j] = 0;
    }
    *(bf16x8*)&Af[(long long)F * 512 + lane * 8] = *(const bf16x8*)v;
}

// C[b][m][n] = sum_k A[m][k]*B[k][n]. B read in [k][n] layout (row stride HW),
// transposed+cvt into slot-swizzled LDS during staging; after one sync each
// wave hoists its full B-frag set to registers and the mb loop is pure MFMA
// with double-buffered A-frag prefetch. 64-col n-tile per block.
template <bool SRC_F32, bool OUT_F32, int NMB>
__global__ __launch_bounds__(256, 2) void gemm_tn(
    const u16* __restrict__ Afrag, const void* __restrict__ Bsrc, void* __restrict__ Cv,
    int M, long long af_bs, long long b_bs, long long c_bs)
{
    __shared__ u16 lsB[6][64 * 32];  // 24 KiB; chunk ks: [n][slot], slot s of
                                     // row n holds kslot s ^ ((n>>1)&3)
    const int tid = threadIdx.x, lane = tid & 63, wid = tid >> 6;
    const int n0 = blockIdx.x * 64;
    const long long bz = blockIdx.z;
    const int lr = lane & 15, quad = lane >> 4;

    // ---- stage B panel (192k x 64n): thread (kg,l5) covers k=r*64+kg*8+j,
    //      cols 2*l5, 2*l5+1.  All 24 loads preloaded, then convert+write.
    {
        const int kg = tid >> 5, l5 = tid & 31;
        const int slot = (kg & 3) ^ (l5 & 3);
        u16* dA = &lsB[0][(2 * l5) * 32 + slot * 8];  // +ck*2048 elems per chunk
        if (SRC_F32) {
            const float* gp = (const float*)Bsrc + bz * b_bs
                            + (long long)(kg * 8) * HW + n0 + 2 * l5;
            f32x2 rv[24];
#pragma unroll
            for (int r = 0; r < 3; r++)
#pragma unroll
                for (int j = 0; j < 8; j++)
                    rv[r * 8 + j] = *(const f32x2*)(gp + ((long long)r * 64 + j) * HW);
#pragma unroll
            for (int r = 0; r < 3; r++) {
                unsigned int lo[4], hi[4];
#pragma unroll
                for (int i = 0; i < 4; i++) {
                    float a0 = rv[r * 8 + 2 * i][0], b0 = rv[r * 8 + 2 * i + 1][0];
                    float a1 = rv[r * 8 + 2 * i][1], b1 = rv[r * 8 + 2 * i + 1][1];
                    asm("v_cvt_pk_bf16_f32 %0, %1, %2" : "=v"(lo[i]) : "v"(a0), "v"(b0));
                    asm("v_cvt_pk_bf16_f32 %0, %1, %2" : "=v"(hi[i]) : "v"(a1), "v"(b1));
                }
                const int ck = r * 2 + (kg >> 2);
                *(u32x4*)(dA + ck * 2048)      = (u32x4){lo[0], lo[1], lo[2], lo[3]};
                *(u32x4*)(dA + ck * 2048 + 32) = (u32x4){hi[0], hi[1], hi[2], hi[3]};
            }
        } else {
            const u16* gp = (const u16*)Bsrc + bz * b_bs
                          + (long long)(kg * 8) * HW + n0 + 2 * l5;
            unsigned int rv[24];
#pragma unroll
            for (int r = 0; r < 3; r++)
#pragma unroll
                for (int j = 0; j < 8; j++)
                    rv[r * 8 + j] = *(const unsigned int*)(gp + ((long long)r * 64 + j) * HW);
#pragma unroll
            for (int r = 0; r < 3; r++) {
                unsigned int lo[4], hi[4];
#pragma unroll
                for (int i = 0; i < 4; i++) {
                    unsigned int e = rv[r * 8 + 2 * i], o = rv[r * 8 + 2 * i + 1];
                    lo[i] = (e & 0xffffu) | (o << 16);
                    hi[i] = (e >> 16) | (o & 0xffff0000u);
                }
                const int ck = r * 2 + (kg >> 2);
                *(u32x4*)(dA + ck * 2048)      = (u32x4){lo[0], lo[1], lo[2], lo[3]};
                *(u32x4*)(dA + ck * 2048 + 32) = (u32x4){hi[0], hi[1], hi[2], hi[3]};
            }
        }
    }

    const u16* ApBase = Afrag + bz * af_bs + lane * 8;
#define LOAD_AF(dst, mbv) do {                                                  \
    const u16* Ap_ = ApBase + (long long)(((mbv) * 2 + (wid >> 1)) * 24) * 512; \
    _Pragma("unroll") for (int mtl_ = 0; mtl_ < 2; mtl_++)                      \
    _Pragma("unroll") for (int ks_ = 0; ks_ < 6; ks_++)                         \
        dst[mtl_][ks_] = *(const bf16x8*)(Ap_ + (((wid & 1) * 2 + mtl_) * 6 + ks_) * 512); \
} while (0)

    bf16x8 af0[2][6], af1[2][6];
    LOAD_AF(af0, 0);           // overlaps the staging drain below
    __syncthreads();           // LDS ready

    // ---- hoist B-frags to registers ONCE (LDS dead afterwards) ----
    const int rslot = (quad ^ ((lr >> 1) & 3)) * 8;  // content kslot == quad
    bf16x8 bfv[6][4];
#pragma unroll
    for (int ks = 0; ks < 6; ks++)
#pragma unroll
        for (int nt = 0; nt < 4; nt++)
            bfv[ks][nt] = *(const bf16x8*)&lsB[ks][(nt * 16 + lr) * 32 + rslot];

    const long long cB = bz * c_bs + n0 + lr;
#define COMPUTE_MB(afb, mbv) do {                                               \
    f32x4 acc[2][4];                                                            \
    _Pragma("unroll") for (int i_ = 0; i_ < 2; i_++)                            \
    _Pragma("unroll") for (int j_ = 0; j_ < 4; j_++)                            \
        acc[i_][j_] = (f32x4){0.f, 0.f, 0.f, 0.f};                              \
    _Pragma("unroll") for (int ks_ = 0; ks_ < 6; ks_++)                         \
    _Pragma("unroll") for (int mtl_ = 0; mtl_ < 2; mtl_++)                      \
    _Pragma("unroll") for (int nt_ = 0; nt_ < 4; nt_++)                         \
        acc[mtl_][nt_] = __builtin_amdgcn_mfma_f32_16x16x32_bf16(               \
            afb[mtl_][ks_], bfv[ks_][nt_], acc[mtl_][nt_], 0, 0, 0);            \
    _Pragma("unroll") for (int mtl_ = 0; mtl_ < 2; mtl_++)                      \
    _Pragma("unroll") for (int r_ = 0; r_ < 4; r_++) {                          \
        const long long ro = cB + (long long)((mbv) * 128 + wid * 32            \
                             + mtl_ * 16 + quad * 4 + r_) * HW;                 \
        _Pragma("unroll") for (int nt_ = 0; nt_ < 4; nt_++) {                   \
            if (OUT_F32) ((float*)Cv)[ro + nt_ * 16] = acc[mtl_][nt_][r_];      \
            else         ((u16*)Cv)[ro + nt_ * 16] = f2b(acc[mtl_][nt_][r_]);   \
        }                                                                       \
    }                                                                           \
} while (0)

#pragma unroll
    for (int mb = 0; mb < NMB; ++mb) {
        if (mb * 128 + wid * 32 >= M) break;   // wave-level mask (M % 32 == 0)
        const bool pf = (mb + 1 < NMB) && ((mb + 1) * 128 + wid * 32 < M);
        if ((mb & 1) == 0) {
            if (pf) LOAD_AF(af1, mb + 1);
            COMPUTE_MB(af0, mb);
        } else {
            if (pf) LOAD_AF(af0, mb + 1);
            COMPUTE_MB(af1, mb);
        }
    }
#undef LOAD_AF
#undef COMPUTE_MB
}

// depthwise 3x3 SAME; in/out bf16, weights fp32 (weight row = wch0 + ch).
__global__ __launch_bounds__(256) void dwconv2(
    const u16* __restrict__ in, const float* __restrict__ wdw, u16* __restrict__ outp,
    long long in_bs, long long out_bs, int wch0)
{
    const int rt = blockIdx.x, ch = blockIdx.y, tid = threadIdx.x;
    const long long bz = blockIdx.z;
    const u16* ip = in + bz * in_bs + (long long)ch * HW;
    u16* op = outp + bz * out_bs + (long long)ch * HW;
    __shared__ float t[18 * 132];
    const int r0 = rt * 16;
    if (tid < 18) {
        t[tid * 132 + 0] = 0.f;   t[tid * 132 + 129] = 0.f;
        t[tid * 132 + 130] = 0.f; t[tid * 132 + 131] = 0.f;
    }
    for (int i = tid; i < 288; i += 256) {
        int rr = i >> 4, cc = (i & 15) * 8;
        int gr = r0 + rr - 1;
        float f[8];
        if (gr >= 0 && gr < 128) {
            bf16x8 v = *(const bf16x8*)(ip + gr * 128 + cc);
#pragma unroll
            for (int j = 0; j < 8; j++) f[j] = b2f((u16)v[j]);
        } else {
#pragma unroll
            for (int j = 0; j < 8; j++) f[j] = 0.f;
        }
#pragma unroll
        for (int j = 0; j < 8; j++) t[rr * 132 + 1 + cc + j] = f[j];
    }
    float w[9];
#pragma unroll
    for (int j = 0; j < 9; j++) w[j] = wdw[(wch0 + ch) * 9 + j];
    __syncthreads();
    const int rr = tid >> 4, c8 = (tid & 15) * 8;
    float o[8] = {0.f, 0.f, 0.f, 0.f, 0.f, 0.f, 0.f, 0.f};
#pragma unroll
    for (int dy = 0; dy < 3; dy++) {
        const float* row = &t[(rr + dy) * 132 + c8];  // LDS idx c8 == image col c8-1
        float r[12] __attribute__((aligned(16)));
        *(f32x4*)&r[0] = *(const f32x4*)row;
        *(f32x4*)&r[4] = *(const f32x4*)(row + 4);
        *(f32x4*)&r[8] = *(const f32x4*)(row + 8);
        const float w0 = w[dy * 3], w1 = w[dy * 3 + 1], w2 = w[dy * 3 + 2];
#pragma unroll
        for (int j = 0; j < 8; j++) o[j] += w0 * r[j] + w1 * r[j + 1] + w2 * r[j + 2];
    }
    u16 ob[8] __attribute__((aligned(16)));
#pragma unroll
    for (int j = 0; j < 8; j++) ob[j] = f2b(o[j]);
    *(bf16x8*)&op[(long long)(r0 + rr) * 128 + c8] = *(const bf16x8*)ob;
}

// S[bh][48][48] += q.k^T ; norms[bh][96] += diag(q.q^T), diag(k.k^T)
__global__ __launch_bounds__(256) void attn_scores(
    const u16* __restrict__ qk, float* __restrict__ S, float* __restrict__ norms,
    int bh0)
{
    const int tid = threadIdx.x, lane = tid & 63, wid = tid >> 6;
    const int kc = blockIdx.x, head = blockIdx.y;
    const long long bz = blockIdx.z;
    const u16* q = qk + bz * (2LL * CD * HW) + (long long)head * 48 * HW;
    const u16* k = q + (long long)CD * HW;
    const int lr = lane & 15, quad = lane >> 4;

    f32x4 sc[3][3], sq[3], sk[3];
#pragma unroll
    for (int i = 0; i < 3; i++) {
#pragma unroll
        for (int j = 0; j < 3; j++) sc[i][j] = (f32x4){0.f, 0.f, 0.f, 0.f};
        sq[i] = (f32x4){0.f, 0.f, 0.f, 0.f};
        sk[i] = (f32x4){0.f, 0.f, 0.f, 0.f};
    }
    const int n0 = kc * 1024 + wid * 256;
#pragma unroll 2
    for (int s = 0; s < 8; s++) {
        const int n = n0 + s * 32 + quad * 8;
        bf16x8 aq[3], ak[3];
#pragma unroll
        for (int t3 = 0; t3 < 3; t3++) {
            aq[t3] = *(const bf16x8*)(q + (long long)(t3 * 16 + lr) * HW + n);
            ak[t3] = *(const bf16x8*)(k + (long long)(t3 * 16 + lr) * HW + n);
        }
#pragma unroll
        for (int mt = 0; mt < 3; mt++)
#pragma unroll
            for (int nt = 0; nt < 3; nt++)
                sc[mt][nt] = __builtin_amdgcn_mfma_f32_16x16x32_bf16(aq[mt], ak[nt], sc[mt][nt], 0, 0, 0);
#pragma unroll
        for (int t3 = 0; t3 < 3; t3++) {
            sq[t3] = __builtin_amdgcn_mfma_f32_16x16x32_bf16(aq[t3], aq[t3], sq[t3], 0, 0, 0);
            sk[t3] = __builtin_amdgcn_mfma_f32_16x16x32_bf16(ak[t3], ak[t3], sk[t3], 0, 0, 0);
        }
    }
    __shared__ float sS[2304];
    __shared__ float snq[48], snk[48];
    for (int i = tid; i < 2304; i += 256) sS[i] = 0.f;
    if (tid < 48) { snq[tid] = 0.f; snk[tid] = 0.f; }
    __syncthreads();
#pragma unroll
    for (int mt = 0; mt < 3; mt++)
#pragma unroll
        for (int nt = 0; nt < 3; nt++)
#pragma unroll
            for (int r = 0; r < 4; r++)
                atomicAdd(&sS[(mt * 16 + quad * 4 + r) * 48 + nt * 16 + lr], sc[mt][nt][r]);
#pragma unroll
    for (int t3 = 0; t3 < 3; t3++)
#pragma unroll
        for (int r = 0; r < 4; r++) {
            int rw = quad * 4 + r;
            if (rw == lr) {
                atomicAdd(&snq[t3 * 16 + rw], sq[t3][r]);
                atomicAdd(&snk[t3 * 16 + rw], sk[t3][r]);
            }
        }
    __syncthreads();
    const int bh = bh0 + (int)bz * 4 + head;
    float* Sg = S + (long long)bh * 2304;
    for (int i = tid; i < 2304; i += 256) atomicAdd(&Sg[i], sS[i]);
    float* ng = norms + bh * 96;
    if (tid < 48) atomicAdd(&ng[tid], snq[tid]);
    else if (tid < 96) atomicAdd(&ng[tid], snk[tid - 48]);
}

__global__ __launch_bounds__(64) void softmax_k(
    const float* __restrict__ S, const float* __restrict__ norms,
    const float* __restrict__ temp, float* __restrict__ attn, int bh0)
{
    const int bh = bh0 + blockIdx.x, head = bh & 3, r = threadIdx.x;
    if (r >= 48) return;
    const float tv = temp[head];
    const float* Sg = S + (long long)bh * 2304;
    const float* ng = norms + bh * 96;
    const float nq = fmaxf(sqrtf(ng[r]), 1e-12f);
    float lg[48];
    float mx = -1e30f;
#pragma unroll
    for (int d = 0; d < 48; d++) {
        float nk = fmaxf(sqrtf(ng[48 + d]), 1e-12f);
        float v = Sg[r * 48 + d] * tv / (nq * nk);
        lg[d] = v; mx = fmaxf(mx, v);
    }
    float sum = 0.f;
#pragma unroll
    for (int d = 0; d < 48; d++) { float e = __expf(lg[d] - mx); lg[d] = e; sum += e; }
    const float inv = 1.f / sum;
    float* Ag = attn + (long long)bh * 2304 + r * 48;
#pragma unroll
    for (int d = 0; d < 48; d++) Ag[d] = lg[d] * inv;
}

// MmF[b] = W_proj . blockdiag(attn), written directly in A-fragment layout.
__global__ __launch_bounds__(256) void mproj(
    const float* __restrict__ wproj, const float* __restrict__ attn, u16* __restrict__ Mm,
    int b0)
{
    const int ob = blockIdx.x, b = b0 + blockIdx.y, tid = threadIdx.x;
    __shared__ float sA[9216];
    const float* Ab = attn + (long long)b * 9216;
    for (int i = tid; i < 9216; i += 256) sA[i] = Ab[i];
    __syncthreads();
    for (int i = tid; i < 48 * 192; i += 256) {
        int o = ob * 48 + i / 192;
        int cc = i % 192;
        int h = cc / 48, d = cc - h * 48;
        const float* wr = wproj + o * 192 + h * 48;
        const float* ar = &sA[h * 2304 + d];
        float acc = 0.f;
        for (int c = 0; c < 48; c++) acc += wr[c] * ar[c * 48];
        // frag-layout store: F = (o>>6)*24 + ((o>>4)&3)*6 + (cc>>5)
        int fi = (o >> 6) * 24 + ((o >> 4) & 3) * 6 + (cc >> 5);
        int lanei = ((cc >> 3) & 3) * 16 + (o & 15);
        Mm[(long long)b * 49152 + (long long)fi * 512 + lanei * 8 + (cc & 7)] = f2b(acc);
    }
}

extern "C" void kernel_launch(void* const* d_in, const int* in_sizes, int n_in,
                              void* d_out, int out_size, void* d_ws, size_t ws_size,
                              hipStream_t stream)
{
    const float* x     = (const float*)d_in[0];
    const float* wqkv  = (const float*)d_in[1];
    const float* wdw   = (const float*)d_in[2];
    const float* temp  = (const float*)d_in[3];
    const float* wproj = (const float*)d_in[4];
    float* out = (float*)d_out;
    char* ws = (char*)d_ws;
    const long long CHW = (long long)CD * HW;

    if (ws_size < 2097152ULL + 31457280ULL) {  // G=1 floor (proved present)
        fill_f32<<<2048, 256, 0, stream>>>(out, out_size, 100.0f);
        return;
    }
    int G = 8;
    while (G > 1 && (unsigned long long)(2097152ULL + (unsigned long long)G * 31457280ULL) > (unsigned long long)ws_size)
        G >>= 1;

    float* S      = (float*)ws;                // 32*2304 f32
    float* norms  = (float*)(ws + 294912);     // 32*96 f32
    float* attn   = (float*)(ws + 307200);     // 32*2304 f32
    u16*   MmF    = (u16*)(ws + 602112);       // 8 * 96 frags * 512 u16
    u16*   wqkvF  = (u16*)(ws + 1388544);      // 240 frags * 512 u16
    u16* region1  = (u16*)(ws + 2097152);      // G*2CHW bf16 (qk_post)
    u16* qkv_pre  = region1 + (long long)G * 2 * CHW;  // G*3CHW bf16

    zerof<<<300, 256, 0, stream>>>(S, 76800);  // S + norms contiguous
    afrag_prep<<<60, 256, 0, stream>>>(wqkv, wqkvF, O3, 240);

    for (int g0 = 0; g0 < 8; g0 += G) {
        // qkv_pre = Wqkv . x  (B = x fp32 [c][p], transposed+cvt in staging)
        gemm_tn<true, false, 5><<<dim3(256, 1, G), 256, 0, stream>>>(
            wqkvF, x + (long long)g0 * CHW, qkv_pre, O3, 0LL, CHW, 3LL * CHW);
        dwconv2<<<dim3(8, 384, G), 256, 0, stream>>>(
            qkv_pre, wdw, region1, 3LL * CHW, 2LL * CHW, 0);
        dwconv2<<<dim3(8, 192, G), 256, 0, stream>>>(
            qkv_pre + 2LL * CHW, wdw, qkv_pre, 3LL * CHW, 3LL * CHW, 384);
        attn_scores<<<dim3(16, 4, G), 256, 0, stream>>>(region1, S, norms, g0 * 4);
        softmax_k<<<4 * G, 64, 0, stream>>>(S, norms, temp, attn, g0 * 4);
        mproj<<<dim3(4, G), 256, 0, stream>>>(wproj, attn, MmF, g0);
        // out = MmF . v_post  (B = qkv_pre ch[0,192) bf16 [c][p])
        gemm_tn<false, true, 2><<<dim3(256, 1, G), 256, 0, stream>>>(
            MmF + (long long)g0 * 49152, qkv_pre, out + (long long)g0 * CHW,
            CD, 49152LL, 3LL * CHW, CHW);
    }
}

// Round 5
// 390.192 us; speedup vs baseline: 1.1179x; 1.0395x over previous
//
#include <hip/hip_runtime.h>
#include <stdint.h>

// Channel attention (Restormer MDTA style). FP32 in/out, bf16 MFMA internals.
// R9: gemm_tn rebuilt around HBM segment size — R4-R8 all sat at 2.2-2.8 TB/s
//   because B-reads were 256B segments @64KB stride (and C-writes 128B @32KB).
//   Now: BN=128 tiles where a WAVE reads one full 512B row segment per load
//   inst (fp32; 2x512B for bf16) — perfectly coalesced staging; full-K LDS
//   residency (48KB, [n][k], XOR-slot swizzle: write slot kslot^((n>>2)&7),
//   conflict-free writes / 2-way reads); B-frags hoisted to regs once; waves
//   split 2m x 2n; m-loop with double-buffered A-frag prefetch pinned by
//   sched_barrier(0); staging 3 pipelined 64-k-row chunks (2 in flight).
//   ~240 VGPR, 2 blocks/CU -> stage(B) overlaps compute(A) across blocks.
// Pipeline per chunk of G batches:
//   gemm_tn<f32,bf16,18>: qkv_pre = Wqkv . x       (M=576)
//   dwconv2 qk    : qkv_pre ch[0,384) -> region1 bf16
//   dwconv2 v     : qkv_pre ch[384,576) -> qkv_pre ch[0,192)
//   attn_scores   : S[bh] += q.k^T, norms += diag MFMA
//   softmax       : attn = softmax(temp * S / (|q||k|))
//   mproj         : MmF[b] = W_proj . blockdiag(attn)  (bf16, frag layout)
//   gemm_tn<bf16,f32,6>: out = MmF . v_post        (M=192)

typedef __attribute__((ext_vector_type(8))) short bf16x8;
typedef __attribute__((ext_vector_type(4))) float f32x4;
typedef __attribute__((ext_vector_type(2))) float f32x2;
typedef __attribute__((ext_vector_type(4))) unsigned int u32x4;
typedef __attribute__((ext_vector_type(2))) unsigned int u32x2;
typedef unsigned short u16;

#define HW 16384
#define CD 192
#define O3 576
#define KD 192

__device__ __forceinline__ float b2f(u16 u) {
    union { unsigned int i; float f; } v; v.i = ((unsigned int)u) << 16; return v.f;
}
__device__ __forceinline__ u16 f2b(float f) {
    union { float f; unsigned int i; } v; v.f = f;
    return (u16)((v.i + 0x7fffu + ((v.i >> 16) & 1u)) >> 16);  // RNE
}

__global__ __launch_bounds__(256) void fill_f32(float* p, long long n, float val) {
    long long stride = (long long)gridDim.x * 256;
    for (long long i = blockIdx.x * 256LL + threadIdx.x; i < n; i += stride) p[i] = val;
}

__global__ __launch_bounds__(256) void zerof(float* p, int n) {
    int i = blockIdx.x * 256 + threadIdx.x;
    if (i < n) p[i] = 0.f;
}

// W fp32 [M][192] -> fragment-layout bf16, rows padded to NF/48*128 with zeros.
// Frag F = rwmb*24 + mt*6 + ks  (rwmb = row>>6), holds rows rwmb*64+mt*16+[0,16)
// x k ks*32+[0,32). Within frag: lane = q*16+lr, lane's 8 k at Af[F*512+lane*8].
__global__ __launch_bounds__(256) void afrag_prep(
    const float* __restrict__ W, u16* __restrict__ Af, int M, int NF)
{
    int t = blockIdx.x * 256 + threadIdx.x;
    if (t >= NF * 64) return;
    int F = t >> 6, lane = t & 63;
    int ks = F % 6, mt = (F / 6) & 3, rwmb = F / 24;
    int row = rwmb * 64 + mt * 16 + (lane & 15);
    int k0 = ks * 32 + (lane >> 4) * 8;
    u16 v[8] __attribute__((aligned(16)));
    if (row < M) {
        const float* src = W + (long long)row * KD + k0;
#pragma unroll
        for (int j = 0; j < 8; j++) v[j] = f2b(src[j]);
    } else {
#pragma unroll
        for (int j = 0; j < 8; j++) v[j] = 0;
    }
    *(bf16x8*)&Af[(long long)F * 512 + lane * 8] = *(const bf16x8*)v;
}

// C[b][m][n] = sum_k A[m][k]*B[k][n]. B in [k][n] (row stride HW elems).
// BN=128 n-tile; staging: wave reads FULL 512B row segments (fp32: 64 lanes x
// f32x4 = 1 row/inst; bf16: 4 rows/inst), repack (cvt_pk / v_perm) into
// swizzled LDS [128n][192k]; 3 chunks of 64 k-rows, 2 in flight.
// After 1 barrier: B-frags hoisted to bfv[6][4] regs (LDS dead), waves split
// 2m x 2n, per-wave m-loop (NMS/2 steps of 32 rows) with double-buffered
// A-frag prefetch. NMS = total 32-row m-steps (M/32).
template <bool SRC_F32, bool OUT_F32, int NMS>
__global__ __launch_bounds__(256, 2) void gemm_tn(
    const u16* __restrict__ Afrag, const void* __restrict__ Bsrc, void* __restrict__ Cv,
    long long af_bs, long long b_bs, long long c_bs)
{
    __shared__ u16 lsB[128 * 192];  // 48 KiB: row n (384B) = 24 slots of 16B
    const int tid = threadIdx.x, lane = tid & 63, wid = tid >> 6;
    const int n0 = blockIdx.x * 128;
    const long long bz = blockIdx.z;
    const int lr = lane & 15, quad = lane >> 4;
    const int wn = wid & 1, wm = wid >> 1;

#define LADDR(n_, ks_) ((n_) * 192 + (((ks_) ^ (((n_) >> 2) & 7)) * 8))

    if (SRC_F32) {
        const int c32 = lane & 31, rs = lane >> 5;
        const float* gp = (const float*)Bsrc + bz * b_bs + n0 + 4 * c32;
        f32x4 bufA[8], bufB[8];
#define LOADC_F(buf, c) do { \
    const float* p_ = gp + (long long)((c) * 64 + wid * 16 + rs * 8) * HW; \
    _Pragma("unroll") for (int i_ = 0; i_ < 8; i_++) \
        buf[i_] = *(const f32x4*)(p_ + (long long)i_ * HW); \
} while (0)
#define PROC_F(buf, c) do { \
    const int kslot_ = (c) * 8 + wid * 2 + rs; \
    _Pragma("unroll") for (int j_ = 0; j_ < 4; j_++) { \
        const int n_ = 4 * c32 + j_; \
        unsigned int p0_, p1_, p2_, p3_; \
        asm("v_cvt_pk_bf16_f32 %0, %1, %2" : "=v"(p0_) : "v"(buf[0][j_]), "v"(buf[1][j_])); \
        asm("v_cvt_pk_bf16_f32 %0, %1, %2" : "=v"(p1_) : "v"(buf[2][j_]), "v"(buf[3][j_])); \
        asm("v_cvt_pk_bf16_f32 %0, %1, %2" : "=v"(p2_) : "v"(buf[4][j_]), "v"(buf[5][j_])); \
        asm("v_cvt_pk_bf16_f32 %0, %1, %2" : "=v"(p3_) : "v"(buf[6][j_]), "v"(buf[7][j_])); \
        *(u32x4*)&lsB[LADDR(n_, kslot_)] = (u32x4){p0_, p1_, p2_, p3_}; \
    } \
} while (0)
        LOADC_F(bufA, 0);
        LOADC_F(bufB, 1);
        __builtin_amdgcn_sched_barrier(0);
        PROC_F(bufA, 0);
        LOADC_F(bufA, 2);
        __builtin_amdgcn_sched_barrier(0);
        PROC_F(bufB, 1);
        PROC_F(bufA, 2);
#undef LOADC_F
#undef PROC_F
    } else {
        const int c16 = lane & 15, rs4 = lane >> 4;
        const u16* gp = (const u16*)Bsrc + bz * b_bs + n0 + 8 * c16;
        u32x4 bufA[4], bufB[4];
#define LOADC_B(buf, c) do { \
    const u16* p_ = gp + (long long)((c) * 64 + wid * 16 + rs4 * 4) * HW; \
    _Pragma("unroll") for (int i_ = 0; i_ < 4; i_++) \
        buf[i_] = *(const u32x4*)(p_ + (long long)i_ * HW); \
} while (0)
#define PROC_B(buf, c) do { \
    const int kslot_ = (c) * 8 + wid * 2 + (rs4 >> 1); \
    const int kh_ = (rs4 & 1) * 4; \
    _Pragma("unroll") for (int j_ = 0; j_ < 4; j_++) { \
        unsigned int l0_ = __builtin_amdgcn_perm(buf[0][j_], buf[1][j_], 0x01000504u); \
        unsigned int l1_ = __builtin_amdgcn_perm(buf[2][j_], buf[3][j_], 0x01000504u); \
        unsigned int h0_ = __builtin_amdgcn_perm(buf[0][j_], buf[1][j_], 0x03020706u); \
        unsigned int h1_ = __builtin_amdgcn_perm(buf[2][j_], buf[3][j_], 0x03020706u); \
        *(u32x2*)&lsB[LADDR(8 * c16 + 2 * j_, kslot_) + kh_] = (u32x2){l0_, l1_}; \
        *(u32x2*)&lsB[LADDR(8 * c16 + 2 * j_ + 1, kslot_) + kh_] = (u32x2){h0_, h1_}; \
    } \
} while (0)
        LOADC_B(bufA, 0);
        LOADC_B(bufB, 1);
        __builtin_amdgcn_sched_barrier(0);
        PROC_B(bufA, 0);
        LOADC_B(bufA, 2);
        __builtin_amdgcn_sched_barrier(0);
        PROC_B(bufB, 1);
        PROC_B(bufA, 2);
#undef LOADC_B
#undef PROC_B
    }
    __syncthreads();  // LDS ready; static for whole kernel

    // ---- hoist B-frags to registers ONCE (LDS dead afterwards) ----
    bf16x8 bfv[6][4];
#pragma unroll
    for (int ks = 0; ks < 6; ks++)
#pragma unroll
        for (int nt = 0; nt < 4; nt++) {
            const int n_ = wn * 64 + nt * 16 + lr;
            bfv[ks][nt] = *(const bf16x8*)&lsB[LADDR(n_, ks * 4 + quad)];
        }
#undef LADDR

    const u16* ApBase = Afrag + bz * af_bs + lane * 8;
    const long long cB = bz * c_bs + n0 + wn * 64 + lr;
    constexpr int NT = NMS / 2;  // m-steps per wave

#define LOAD_AF(dst, sv) do { \
    _Pragma("unroll") for (int mtl_ = 0; mtl_ < 2; mtl_++) \
    _Pragma("unroll") for (int ks_ = 0; ks_ < 6; ks_++) \
        dst[mtl_][ks_] = *(const bf16x8*)(ApBase + \
            (long long)(((sv) >> 1) * 24 + (((sv) & 1) * 2 + mtl_) * 6 + ks_) * 512); \
} while (0)
#define COMPUTE_MB(afb, sv) do { \
    f32x4 acc_[2][4]; \
    _Pragma("unroll") for (int i_ = 0; i_ < 2; i_++) \
    _Pragma("unroll") for (int j_ = 0; j_ < 4; j_++) \
        acc_[i_][j_] = (f32x4){0.f, 0.f, 0.f, 0.f}; \
    _Pragma("unroll") for (int ks_ = 0; ks_ < 6; ks_++) \
    _Pragma("unroll") for (int mtl_ = 0; mtl_ < 2; mtl_++) \
    _Pragma("unroll") for (int nt_ = 0; nt_ < 4; nt_++) \
        acc_[mtl_][nt_] = __builtin_amdgcn_mfma_f32_16x16x32_bf16( \
            afb[mtl_][ks_], bfv[ks_][nt_], acc_[mtl_][nt_], 0, 0, 0); \
    _Pragma("unroll") for (int mtl_ = 0; mtl_ < 2; mtl_++) \
    _Pragma("unroll") for (int r_ = 0; r_ < 4; r_++) { \
        const long long ro_ = cB + (long long)(32 * (sv) + mtl_ * 16 + quad * 4 + r_) * HW; \
        _Pragma("unroll") for (int nt_ = 0; nt_ < 4; nt_++) { \
            if (OUT_F32) ((float*)Cv)[ro_ + nt_ * 16] = acc_[mtl_][nt_][r_]; \
            else         ((u16*)Cv)[ro_ + nt_ * 16] = f2b(acc_[mtl_][nt_][r_]); \
        } \
    } \
} while (0)

    bf16x8 afA[2][6], afB[2][6];
    const int s0 = wm * NT;
    LOAD_AF(afA, s0);
#pragma unroll
    for (int t = 0; t < NT; ++t) {
        if (t + 1 < NT) {
            if (t & 1) LOAD_AF(afA, s0 + t + 1);
            else       LOAD_AF(afB, s0 + t + 1);
            __builtin_amdgcn_sched_barrier(0);  // keep prefetch ahead of MFMAs
        }
        if (t & 1) COMPUTE_MB(afB, s0 + t);
        else       COMPUTE_MB(afA, s0 + t);
    }
#undef LOAD_AF
#undef COMPUTE_MB
}

// depthwise 3x3 SAME; in/out bf16, weights fp32 (weight row = wch0 + ch).
__global__ __launch_bounds__(256) void dwconv2(
    const u16* __restrict__ in, const float* __restrict__ wdw, u16* __restrict__ outp,
    long long in_bs, long long out_bs, int wch0)
{
    const int rt = blockIdx.x, ch = blockIdx.y, tid = threadIdx.x;
    const long long bz = blockIdx.z;
    const u16* ip = in + bz * in_bs + (long long)ch * HW;
    u16* op = outp + bz * out_bs + (long long)ch * HW;
    __shared__ float t[18 * 132];
    const int r0 = rt * 16;
    if (tid < 18) {
        t[tid * 132 + 0] = 0.f;   t[tid * 132 + 129] = 0.f;
        t[tid * 132 + 130] = 0.f; t[tid * 132 + 131] = 0.f;
    }
    for (int i = tid; i < 288; i += 256) {
        int rr = i >> 4, cc = (i & 15) * 8;
        int gr = r0 + rr - 1;
        float f[8];
        if (gr >= 0 && gr < 128) {
            bf16x8 v = *(const bf16x8*)(ip + gr * 128 + cc);
#pragma unroll
            for (int j = 0; j < 8; j++) f[j] = b2f((u16)v[j]);
        } else {
#pragma unroll
            for (int j = 0; j < 8; j++) f[j] = 0.f;
        }
#pragma unroll
        for (int j = 0; j < 8; j++) t[rr * 132 + 1 + cc + j] = f[j];
    }
    float w[9];
#pragma unroll
    for (int j = 0; j < 9; j++) w[j] = wdw[(wch0 + ch) * 9 + j];
    __syncthreads();
    const int rr = tid >> 4, c8 = (tid & 15) * 8;
    float o[8] = {0.f, 0.f, 0.f, 0.f, 0.f, 0.f, 0.f, 0.f};
#pragma unroll
    for (int dy = 0; dy < 3; dy++) {
        const float* row = &t[(rr + dy) * 132 + c8];  // LDS idx c8 == image col c8-1
        float r[12] __attribute__((aligned(16)));
        *(f32x4*)&r[0] = *(const f32x4*)row;
        *(f32x4*)&r[4] = *(const f32x4*)(row + 4);
        *(f32x4*)&r[8] = *(const f32x4*)(row + 8);
        const float w0 = w[dy * 3], w1 = w[dy * 3 + 1], w2 = w[dy * 3 + 2];
#pragma unroll
        for (int j = 0; j < 8; j++) o[j] += w0 * r[j] + w1 * r[j + 1] + w2 * r[j + 2];
    }
    u16 ob[8] __attribute__((aligned(16)));
#pragma unroll
    for (int j = 0; j < 8; j++) ob[j] = f2b(o[j]);
    *(bf16x8*)&op[(long long)(r0 + rr) * 128 + c8] = *(const bf16x8*)ob;
}

// S[bh][48][48] += q.k^T ; norms[bh][96] += diag(q.q^T), diag(k.k^T)
__global__ __launch_bounds__(256) void attn_scores(
    const u16* __restrict__ qk, float* __restrict__ S, float* __restrict__ norms,
    int bh0)
{
    const int tid = threadIdx.x, lane = tid & 63, wid = tid >> 6;
    const int kc = blockIdx.x, head = blockIdx.y;
    const long long bz = blockIdx.z;
    const u16* q = qk + bz * (2LL * CD * HW) + (long long)head * 48 * HW;
    const u16* k = q + (long long)CD * HW;
    const int lr = lane & 15, quad = lane >> 4;

    f32x4 sc[3][3], sq[3], sk[3];
#pragma unroll
    for (int i = 0; i < 3; i++) {
#pragma unroll
        for (int j = 0; j < 3; j++) sc[i][j] = (f32x4){0.f, 0.f, 0.f, 0.f};
        sq[i] = (f32x4){0.f, 0.f, 0.f, 0.f};
        sk[i] = (f32x4){0.f, 0.f, 0.f, 0.f};
    }
    const int n0 = kc * 1024 + wid * 256;
#pragma unroll 2
    for (int s = 0; s < 8; s++) {
        const int n = n0 + s * 32 + quad * 8;
        bf16x8 aq[3], ak[3];
#pragma unroll
        for (int t3 = 0; t3 < 3; t3++) {
            aq[t3] = *(const bf16x8*)(q + (long long)(t3 * 16 + lr) * HW + n);
            ak[t3] = *(const bf16x8*)(k + (long long)(t3 * 16 + lr) * HW + n);
        }
#pragma unroll
        for (int mt = 0; mt < 3; mt++)
#pragma unroll
            for (int nt = 0; nt < 3; nt++)
                sc[mt][nt] = __builtin_amdgcn_mfma_f32_16x16x32_bf16(aq[mt], ak[nt], sc[mt][nt], 0, 0, 0);
#pragma unroll
        for (int t3 = 0; t3 < 3; t3++) {
            sq[t3] = __builtin_amdgcn_mfma_f32_16x16x32_bf16(aq[t3], aq[t3], sq[t3], 0, 0, 0);
            sk[t3] = __builtin_amdgcn_mfma_f32_16x16x32_bf16(ak[t3], ak[t3], sk[t3], 0, 0, 0);
        }
    }
    __shared__ float sS[2304];
    __shared__ float snq[48], snk[48];
    for (int i = tid; i < 2304; i += 256) sS[i] = 0.f;
    if (tid < 48) { snq[tid] = 0.f; snk[tid] = 0.f; }
    __syncthreads();
#pragma unroll
    for (int mt = 0; mt < 3; mt++)
#pragma unroll
        for (int nt = 0; nt < 3; nt++)
#pragma unroll
            for (int r = 0; r < 4; r++)
                atomicAdd(&sS[(mt * 16 + quad * 4 + r) * 48 + nt * 16 + lr], sc[mt][nt][r]);
#pragma unroll
    for (int t3 = 0; t3 < 3; t3++)
#pragma unroll
        for (int r = 0; r < 4; r++) {
            int rw = quad * 4 + r;
            if (rw == lr) {
                atomicAdd(&snq[t3 * 16 + rw], sq[t3][r]);
                atomicAdd(&snk[t3 * 16 + rw], sk[t3][r]);
            }
        }
    __syncthreads();
    const int bh = bh0 + (int)bz * 4 + head;
    float* Sg = S + (long long)bh * 2304;
    for (int i = tid; i < 2304; i += 256) atomicAdd(&Sg[i], sS[i]);
    float* ng = norms + bh * 96;
    if (tid < 48) atomicAdd(&ng[tid], snq[tid]);
    else if (tid < 96) atomicAdd(&ng[tid], snk[tid - 48]);
}

__global__ __launch_bounds__(64) void softmax_k(
    const float* __restrict__ S, const float* __restrict__ norms,
    const float* __restrict__ temp, float* __restrict__ attn, int bh0)
{
    const int bh = bh0 + blockIdx.x, head = bh & 3, r = threadIdx.x;
    if (r >= 48) return;
    const float tv = temp[head];
    const float* Sg = S + (long long)bh * 2304;
    const float* ng = norms + bh * 96;
    const float nq = fmaxf(sqrtf(ng[r]), 1e-12f);
    float lg[48];
    float mx = -1e30f;
#pragma unroll
    for (int d = 0; d < 48; d++) {
        float nk = fmaxf(sqrtf(ng[48 + d]), 1e-12f);
        float v = Sg[r * 48 + d] * tv / (nq * nk);
        lg[d] = v; mx = fmaxf(mx, v);
    }
    float sum = 0.f;
#pragma unroll
    for (int d = 0; d < 48; d++) { float e = __expf(lg[d] - mx); lg[d] = e; sum += e; }
    const float inv = 1.f / sum;
    float* Ag = attn + (long long)bh * 2304 + r * 48;
#pragma unroll
    for (int d = 0; d < 48; d++) Ag[d] = lg[d] * inv;
}

// MmF[b] = W_proj . blockdiag(attn), written directly in A-fragment layout.
__global__ __launch_bounds__(256) void mproj(
    const float* __restrict__ wproj, const float* __restrict__ attn, u16* __restrict__ Mm,
    int b0)
{
    const int ob = blockIdx.x, b = b0 + blockIdx.y, tid = threadIdx.x;
    __shared__ float sA[9216];
    const float* Ab = attn + (long long)b * 9216;
    for (int i = tid; i < 9216; i += 256) sA[i] = Ab[i];
    __syncthreads();
    for (int i = tid; i < 48 * 192; i += 256) {
        int o = ob * 48 + i / 192;
        int cc = i % 192;
        int h = cc / 48, d = cc - h * 48;
        const float* wr = wproj + o * 192 + h * 48;
        const float* ar = &sA[h * 2304 + d];
        float acc = 0.f;
        for (int c = 0; c < 48; c++) acc += wr[c] * ar[c * 48];
        // frag-layout store: F = (o>>6)*24 + ((o>>4)&3)*6 + (cc>>5)
        int fi = (o >> 6) * 24 + ((o >> 4) & 3) * 6 + (cc >> 5);
        int lanei = ((cc >> 3) & 3) * 16 + (o & 15);
        Mm[(long long)b * 49152 + (long long)fi * 512 + lanei * 8 + (cc & 7)] = f2b(acc);
    }
}

extern "C" void kernel_launch(void* const* d_in, const int* in_sizes, int n_in,
                              void* d_out, int out_size, void* d_ws, size_t ws_size,
                              hipStream_t stream)
{
    const float* x     = (const float*)d_in[0];
    const float* wqkv  = (const float*)d_in[1];
    const float* wdw   = (const float*)d_in[2];
    const float* temp  = (const float*)d_in[3];
    const float* wproj = (const float*)d_in[4];
    float* out = (float*)d_out;
    char* ws = (char*)d_ws;
    const long long CHW = (long long)CD * HW;

    if (ws_size < 2097152ULL + 31457280ULL) {  // G=1 floor (proved present)
        fill_f32<<<2048, 256, 0, stream>>>(out, out_size, 100.0f);
        return;
    }
    int G = 8;
    while (G > 1 && (unsigned long long)(2097152ULL + (unsigned long long)G * 31457280ULL) > (unsigned long long)ws_size)
        G >>= 1;

    float* S      = (float*)ws;                // 32*2304 f32
    float* norms  = (float*)(ws + 294912);     // 32*96 f32
    float* attn   = (float*)(ws + 307200);     // 32*2304 f32
    u16*   MmF    = (u16*)(ws + 602112);       // 8 * 96 frags * 512 u16
    u16*   wqkvF  = (u16*)(ws + 1388544);      // 240 frags * 512 u16
    u16* region1  = (u16*)(ws + 2097152);      // G*2CHW bf16 (qk_post)
    u16* qkv_pre  = region1 + (long long)G * 2 * CHW;  // G*3CHW bf16

    zerof<<<300, 256, 0, stream>>>(S, 76800);  // S + norms contiguous
    afrag_prep<<<60, 256, 0, stream>>>(wqkv, wqkvF, O3, 240);

    for (int g0 = 0; g0 < 8; g0 += G) {
        // qkv_pre = Wqkv . x  (B = x fp32 [c][p], transposed+cvt in staging)
        gemm_tn<true, false, 18><<<dim3(128, 1, G), 256, 0, stream>>>(
            wqkvF, x + (long long)g0 * CHW, qkv_pre, 0LL, CHW, 3LL * CHW);
        dwconv2<<<dim3(8, 384, G), 256, 0, stream>>>(
            qkv_pre, wdw, region1, 3LL * CHW, 2LL * CHW, 0);
        dwconv2<<<dim3(8, 192, G), 256, 0, stream>>>(
            qkv_pre + 2LL * CHW, wdw, qkv_pre, 3LL * CHW, 3LL * CHW, 384);
        attn_scores<<<dim3(16, 4, G), 256, 0, stream>>>(region1, S, norms, g0 * 4);
        softmax_k<<<4 * G, 64, 0, stream>>>(S, norms, temp, attn, g0 * 4);
        mproj<<<dim3(4, G), 256, 0, stream>>>(wproj, attn, MmF, g0);
        // out = MmF . v_post  (B = qkv_pre ch[0,192) bf16 [c][p])
        gemm_tn<false, true, 6><<<dim3(128, 1, G), 256, 0, stream>>>(
            MmF + (long long)g0 * 49152, qkv_pre, out + (long long)g0 * CHW,
            49152LL, 3LL * CHW, CHW);
    }
}